// Round 4
// baseline (14194.424 us; speedup 1.0000x reference)
//
#include <hip/hip_runtime.h>
#include <math.h>

namespace {

constexpr int kNL = 24, kD = 768, kDi = 1536, kN = 16, kR = 48, kK = 4, kV = 50280, kNH = 12;
constexpr int kB = 4, kS = 256;
constexpr int kMtok = kB * kS;   // 1024 token rows
constexpr int kMref = kB * kNL;  // 96 refine rows
constexpr int kVp = 50304;       // kV padded to 128

using bf16x8 = __attribute__((ext_vector_type(8))) short;
using f32x4  = __attribute__((ext_vector_type(4))) float;

__device__ __forceinline__ float siluf(float x) { return x / (1.f + __expf(-x)); }

__device__ __forceinline__ ushort f2b(float f) {
    union { float f; unsigned u; } v; v.f = f;
    unsigned u = v.u;
    unsigned r = (u + 0x7FFFu + ((u >> 16) & 1u)) >> 16;
    return (ushort)r;
}

#define GLOAD_LDS(g, l) \
    __builtin_amdgcn_global_load_lds((const __attribute__((address_space(1))) void*)(g), \
                                     (__attribute__((address_space(3))) void*)(l), 16, 0, 0)

// ---------------- bf16 MFMA GEMM: C[M,N] = A[M,K] @ B[N,K]^T ----------------
// BK=64, double-buffered LDS, prefetch-then-compute, XOR-swizzled LDS
// (linear global_load_lds dest + inverse-swizzled global source col +
//  swizzled ds_read slot — rule #21 both-sides involution).
// ACT: 0 none, 1 softplus, 2 gelu(exact).
// OUTMODE: 0 fp32 C; 1 fp32 C + bf16 Cbf; 2 bf16 Cbf only; 3 x_proj special
//          (gn<48 -> bf16 dt-in (Cbf, ld 64), cols 48..63 zeroed; gn in
//          [48,80) -> fp32 B/C buffer (C, ld 32)).
template <int BM, int BN, int BIAS, int ACT, int RES, int OUTMODE>
__global__ __launch_bounds__(256, ((BM + BN) <= 128 ? 4 : 2)) void gemm_bf16(
    const ushort* __restrict__ A, int lda,
    const ushort* __restrict__ B, int ldb,
    float* __restrict__ C, int ldc,
    ushort* __restrict__ Cbf, int ldcb,
    const float* __restrict__ bias,
    int M, int N, int K)
{
    constexpr int ACH = BM / 32;   // global_load_lds issues per wave for A per K64 step
    constexpr int BCH = BN / 32;
    constexpr int MI  = BM / 32;   // 16-row fragments per wave
    constexpr int NJ  = BN / 32;

    __shared__ ushort As[2][BM * 64];
    __shared__ ushort Bs[2][BN * 64];

    const int tid  = threadIdx.x;
    const int lane = tid & 63;
    const int wave = tid >> 6;
    const int m0 = blockIdx.y * BM;
    const int n0 = blockIdx.x * BN;
    const int wr = (wave >> 1) * (BM / 2);
    const int wc = (wave & 1) * (BN / 2);

    f32x4 acc[MI][NJ];
#pragma unroll
    for (int i = 0; i < MI; ++i)
#pragma unroll
        for (int j = 0; j < NJ; ++j) acc[i][j] = f32x4{0.f, 0.f, 0.f, 0.f};

    // staging: chunk c = g*4+wave covers rows c*8..c*8+7 of the tile.
    // lane l -> row c*8 + (l>>3); source col pre-swizzled: ((l&7)^(l>>3))*8
    const int srow = lane >> 3;
    const int scol = ((lane & 7) ^ srow) * 8;
    const ushort* gA[ACH];
    const ushort* gB[BCH];
#pragma unroll
    for (int g = 0; g < ACH; ++g)
        gA[g] = A + (size_t)(m0 + (g * 4 + wave) * 8 + srow) * lda + scol;
#pragma unroll
    for (int g = 0; g < BCH; ++g)
        gB[g] = B + (size_t)(n0 + (g * 4 + wave) * 8 + srow) * ldb + scol;

    const int frow = lane & 15;
    const int kh   = lane >> 4;   // 0..3, fragment k-chunk = kh*8 within a K32 slice
    const int nt   = K >> 6;

    // prologue: stage tile 0 into buffer 0
#pragma unroll
    for (int g = 0; g < ACH; ++g) GLOAD_LDS(gA[g], &As[0][(g * 4 + wave) * 512]);
#pragma unroll
    for (int g = 0; g < BCH; ++g) GLOAD_LDS(gB[g], &Bs[0][(g * 4 + wave) * 512]);
    __syncthreads();

    int cur = 0;
    for (int t = 0; t < nt; ++t) {
        if (t + 1 < nt) {
            const int off = (t + 1) * 64;
#pragma unroll
            for (int g = 0; g < ACH; ++g) GLOAD_LDS(gA[g] + off, &As[cur ^ 1][(g * 4 + wave) * 512]);
#pragma unroll
            for (int g = 0; g < BCH; ++g) GLOAD_LDS(gB[g] + off, &Bs[cur ^ 1][(g * 4 + wave) * 512]);
        }
#pragma unroll
        for (int s = 0; s < 2; ++s) {
            bf16x8 fa[MI], fb[NJ];
#pragma unroll
            for (int i = 0; i < MI; ++i) {
                int r = wr + i * 16 + frow;
                int slot = (s * 4 + kh) ^ (r & 7);
                fa[i] = *(const bf16x8*)&As[cur][r * 64 + slot * 8];
            }
#pragma unroll
            for (int j = 0; j < NJ; ++j) {
                int r = wc + j * 16 + frow;
                int slot = (s * 4 + kh) ^ (r & 7);
                fb[j] = *(const bf16x8*)&Bs[cur][r * 64 + slot * 8];
            }
#pragma unroll
            for (int i = 0; i < MI; ++i)
#pragma unroll
                for (int j = 0; j < NJ; ++j)
                    acc[i][j] = __builtin_amdgcn_mfma_f32_16x16x32_bf16(fa[i], fb[j], acc[i][j], 0, 0, 0);
        }
        __syncthreads();
        cur ^= 1;
    }

    // epilogue: C/D layout col = lane&15, row = (lane>>4)*4 + q
    const int ccol = lane & 15;
    const int crow = (lane >> 4) * 4;
#pragma unroll
    for (int i = 0; i < MI; ++i) {
#pragma unroll
        for (int j = 0; j < NJ; ++j) {
            int gn = n0 + wc + j * 16 + ccol;
            if (gn >= N) continue;
            float bv = BIAS ? bias[gn] : 0.f;
#pragma unroll
            for (int q = 0; q < 4; ++q) {
                int gm = m0 + wr + i * 16 + crow + q;
                if (gm >= M) continue;
                float v = acc[i][j][q] + bv;
                if (ACT == 1) v = fmaxf(v, 0.f) + log1pf(expf(-fabsf(v)));
                if (ACT == 2) v = 0.5f * v * (1.f + erff(v * 0.70710678118654752f));
                if (OUTMODE == 3) {
                    if (gn < 48) Cbf[(size_t)gm * 64 + gn] = f2b(v);
                    else if (gn < 64) { Cbf[(size_t)gm * 64 + gn] = 0; C[(size_t)gm * 32 + (gn - 48)] = v; }
                    else if (gn < 80) C[(size_t)gm * 32 + (gn - 48)] = v;
                } else {
                    size_t ci = (size_t)gm * ldc + gn;
                    if (RES) v += C[ci];
                    if (OUTMODE != 2) C[ci] = v;
                    if (OUTMODE == 1 || OUTMODE == 2) Cbf[(size_t)gm * ldcb + gn] = f2b(v);
                }
            }
        }
    }
}

template <int BM, int BN, int BIAS, int ACT, int RES, int OUTMODE>
static void gemm(const ushort* A, int lda, const ushort* B, int ldb,
                 float* C, int ldc, ushort* Cb, int ldcb,
                 const float* bias, int M, int N, int K, hipStream_t s)
{
    dim3 g((N + BN - 1) / BN, (M + BM - 1) / BM);
    gemm_bf16<BM, BN, BIAS, ACT, RES, OUTMODE><<<g, dim3(256), 0, s>>>(A, lda, B, ldb, C, ldc, Cb, ldcb, bias, M, N, K);
}

// ---------------- conversions ----------------
__global__ void cvt_kernel(const float* __restrict__ src, ushort* __restrict__ dst, int n) {
    int i = (blockIdx.x * 256 + threadIdx.x) * 4;
    if (i >= n) return;
    float4 v = *(const float4*)(src + i);
    ushort4 o; o.x = f2b(v.x); o.y = f2b(v.y); o.z = f2b(v.z); o.w = f2b(v.w);
    *(ushort4*)(dst + i) = o;
}

// xpw [24][80][1536] -> padded [24][128][1536]
__global__ void cvt_xpw_kernel(const float* __restrict__ src, ushort* __restrict__ dst) {
    int i = (blockIdx.x * 256 + threadIdx.x) * 4;
    if (i >= 24 * 80 * 1536) return;
    int l = i / (80 * 1536), r = i - l * (80 * 1536);
    int row = r / 1536, col = r - row * 1536;
    float4 v = *(const float4*)(src + i);
    ushort4 o; o.x = f2b(v.x); o.y = f2b(v.y); o.z = f2b(v.z); o.w = f2b(v.w);
    *(ushort4*)(dst + ((size_t)(l * 128 + row)) * 1536 + col) = o;
}

// dpw [24][1536][48] -> padded [24][1536][64] (K-pad zero)
__global__ void cvt_dpw_kernel(const float* __restrict__ src, ushort* __restrict__ dst) {
    int i = blockIdx.x * 256 + threadIdx.x;
    if (i >= 24 * 1536 * 64) return;
    int col = i & 63, row = i >> 6;
    dst[i] = (col < 48) ? f2b(src[(size_t)row * 48 + col]) : (ushort)0;
}

// ---------------- embedding ----------------
__global__ void embed_kernel(const int* __restrict__ ids, const int* __restrict__ msk,
                             const float* __restrict__ embed, float* __restrict__ h)
{
    int i = blockIdx.x * 256 + threadIdx.x;
    int row = i / kD, col = i - row * kD;
    h[i] = embed[(size_t)ids[row] * kD + col] * (float)msk[row];
}

// ---------------- RMSNorm -> bf16 ----------------
__global__ __launch_bounds__(256) void rms_kernel(const float* __restrict__ x,
                                                  const float* __restrict__ w,
                                                  ushort* __restrict__ out)
{
    __shared__ float red[256];
    int row = blockIdx.x, tid = threadIdx.x;
    const float* xr = x + (size_t)row * kD;
    float s = 0.f;
    for (int j = tid; j < kD; j += 256) { float v = xr[j]; s += v * v; }
    red[tid] = s; __syncthreads();
    for (int o = 128; o > 0; o >>= 1) { if (tid < o) red[tid] += red[tid + o]; __syncthreads(); }
    float rs = rsqrtf(red[0] / (float)kD + 1e-5f);
    for (int j = tid; j < kD; j += 256) out[(size_t)row * kD + j] = f2b(xr[j] * rs * w[j]);
}

// ---------------- LayerNorm -> bf16 ----------------
__global__ __launch_bounds__(256) void ln_kernel(const float* __restrict__ x,
                                                 const float* __restrict__ w,
                                                 const float* __restrict__ b,
                                                 ushort* __restrict__ out)
{
    __shared__ float r1[256], r2[256];
    int row = blockIdx.x, tid = threadIdx.x;
    const float* xr = x + (size_t)row * kD;
    float s = 0.f, s2 = 0.f;
    for (int j = tid; j < kD; j += 256) { float v = xr[j]; s += v; s2 += v * v; }
    r1[tid] = s; r2[tid] = s2; __syncthreads();
    for (int o = 128; o > 0; o >>= 1) {
        if (tid < o) { r1[tid] += r1[tid + o]; r2[tid] += r2[tid + o]; }
        __syncthreads();
    }
    float mean = r1[0] / (float)kD;
    float var = r2[0] / (float)kD - mean * mean;
    float rs = rsqrtf(var + 1e-5f);
    for (int j = tid; j < kD; j += 256)
        out[(size_t)row * kD + j] = f2b((xr[j] - mean) * rs * w[j] + b[j]);
}

// ---------------- causal conv (K=4) + bias + silu ----------
__global__ void conv_kernel(const float* __restrict__ xz, const float* __restrict__ cw,
                            const float* __restrict__ cb, float* __restrict__ xc,
                            ushort* __restrict__ xc_bf)
{
    int i = blockIdx.x * 256 + threadIdx.x;   // kMtok * kDi
    int bt = i / kDi, d = i - bt * kDi;
    int b = bt / kS, t = bt - b * kS;
    float s = cb[d];
#pragma unroll
    for (int k = 0; k < kK; ++k) {
        int tt = t - (kK - 1) + k;
        if (tt >= 0) s += xz[(size_t)(b * kS + tt) * (2 * kDi) + d] * cw[d * kK + k];
    }
    float v = siluf(s);
    xc[i] = v;
    xc_bf[i] = f2b(v);
}

// ---------------- selective scan + gating (register-prefetched) -----------
__global__ __launch_bounds__(256) void scan_kernel(
    const float* __restrict__ dlt, const float* __restrict__ xc,
    const float* __restrict__ xz, const float* __restrict__ bc,
    const float* __restrict__ alog, const float* __restrict__ dp,
    float* __restrict__ states, ushort* __restrict__ y)
{
    int gid = blockIdx.x * 256 + threadIdx.x;    // kB*kDi*kN threads
    int n = gid & 15;
    int d = (gid >> 4) % kDi;
    int b = gid / (kDi * kN);
    float Areg = -__expf(alog[d * kN + n]);
    float dpv = dp[d];
    size_t sidx = (size_t)(b * kDi + d) * kN + n;
    float hs = states[sidx];
    size_t bt0 = (size_t)b * kS;
    float dv = dlt[bt0 * kDi + d];
    float xv = xc[bt0 * kDi + d];
    float Bv = bc[bt0 * 32 + n];
    float Cv = bc[bt0 * 32 + 16 + n];
    for (int t = 0; t < kS; ++t) {
        float dvn = 0.f, xvn = 0.f, Bvn = 0.f, Cvn = 0.f;
        if (t + 1 < kS) {
            size_t bt1 = bt0 + t + 1;
            dvn = dlt[bt1 * kDi + d];
            xvn = xc[bt1 * kDi + d];
            Bvn = bc[bt1 * 32 + n];
            Cvn = bc[bt1 * 32 + 16 + n];
        }
        hs = __expf(dv * Areg) * hs + (dv * xv) * Bv;
        float p = hs * Cv;
        p += __shfl_xor(p, 1, 16);
        p += __shfl_xor(p, 2, 16);
        p += __shfl_xor(p, 4, 16);
        p += __shfl_xor(p, 8, 16);
        if (n == 0) {
            size_t bt = bt0 + t;
            float zv = xz[bt * (2 * kDi) + kDi + d];
            y[bt * kDi + d] = f2b((p + xv * dpv) * siluf(zv));
        }
        dv = dvn; xv = xvn; Bv = Bvn; Cv = Cvn;
    }
    states[sidx] = hs;
}

// ---------------- refine: d = states . C_w -> bf16 [row, di] --------------
__global__ void contract_kernel(const float* __restrict__ st, const float* __restrict__ Cw,
                                ushort* __restrict__ dDi)
{
    int i = blockIdx.x * 256 + threadIdx.x;      // kMref * kDi
    int row = i / kDi, di = i - row * kDi;
    int b = row / kNL, s = row - b * kNL;
    const float* sp = st + ((size_t)(s * kB + b) * kDi + di) * kN;
    float acc = 0.f;
#pragma unroll
    for (int nn = 0; nn < kN; ++nn) acc += sp[nn] * Cw[nn];
    dDi[i] = f2b(acc);
}

// ---------------- refine: states += d1536*B_w, then dDi = states . C_w ----
__global__ void update_contract_kernel(const float* __restrict__ d1536,
                                       const float* __restrict__ Bw,
                                       float* __restrict__ st,
                                       const float* __restrict__ Cw,
                                       ushort* __restrict__ dDi)
{
    int i = blockIdx.x * 256 + threadIdx.x;      // kMref * kDi
    int row = i / kDi, di = i - row * kDi;
    int b = row / kNL, s = row - b * kNL;
    float dv = d1536[i];
    float* sp = st + ((size_t)(s * kB + b) * kDi + di) * kN;
    float acc = 0.f;
#pragma unroll
    for (int nn = 0; nn < kN; ++nn) {
        float v = sp[nn] + dv * Bw[nn];
        sp[nn] = v;
        acc += v * Cw[nn];
    }
    dDi[i] = f2b(acc);
}

// ---------------- tiny attention (B=4, S=24, 12 heads, hd=64) -> bf16 -----
__global__ __launch_bounds__(32) void attn_kernel(const float* __restrict__ qkv,
                                                  ushort* __restrict__ o)
{
    int b = blockIdx.x / kNH;
    int hh = blockIdx.x - b * kNH;
    int sq = threadIdx.x;
    if (sq >= kNL) return;
    const float* qrow = qkv + (size_t)(b * kNL + sq) * (3 * kD) + hh * 64;
    float q[64];
#pragma unroll
    for (int e = 0; e < 64; ++e) q[e] = qrow[e];
    float sc[kNL];
    float mx = -1e30f;
    for (int sk = 0; sk < kNL; ++sk) {
        const float* krow = qkv + (size_t)(b * kNL + sk) * (3 * kD) + kD + hh * 64;
        float dt = 0.f;
#pragma unroll
        for (int e = 0; e < 64; ++e) dt += q[e] * krow[e];
        dt *= 0.125f;
        sc[sk] = dt;
        mx = fmaxf(mx, dt);
    }
    float sum = 0.f;
    for (int sk = 0; sk < kNL; ++sk) { sc[sk] = expf(sc[sk] - mx); sum += sc[sk]; }
    float inv = 1.f / sum;
    float out[64];
#pragma unroll
    for (int e = 0; e < 64; ++e) out[e] = 0.f;
    for (int sk = 0; sk < kNL; ++sk) {
        float wgt = sc[sk] * inv;
        const float* vrow = qkv + (size_t)(b * kNL + sk) * (3 * kD) + 2 * kD + hh * 64;
#pragma unroll
        for (int e = 0; e < 64; ++e) out[e] += wgt * vrow[e];
    }
    ushort* orow = o + (size_t)(b * kNL + sq) * kD + hh * 64;
#pragma unroll
    for (int e = 0; e < 64; ++e) orow[e] = f2b(out[e]);
}

} // namespace

extern "C" void kernel_launch(void* const* d_in, const int* in_sizes, int n_in,
                              void* d_out, int out_size, void* d_ws, size_t ws_size,
                              hipStream_t stream)
{
    const int*   q_ids  = (const int*)d_in[0];
    const int*   q_msk  = (const int*)d_in[1];
    const int*   a_ids  = (const int*)d_in[2];
    const int*   a_msk  = (const int*)d_in[3];
    const float* embed  = (const float*)d_in[4];
    const float* norm_w = (const float*)d_in[5];
    const float* ipw    = (const float*)d_in[6];
    const float* cw     = (const float*)d_in[7];
    const float* cb     = (const float*)d_in[8];
    const float* xpw    = (const float*)d_in[9];
    const float* dpw    = (const float*)d_in[10];
    const float* dpb    = (const float*)d_in[11];
    const float* alog   = (const float*)d_in[12];
    const float* dpp    = (const float*)d_in[13];
    const float* opw    = (const float*)d_in[14];
    const float* norm_f = (const float*)d_in[15];
    const float* ln1w   = (const float*)d_in[16];
    const float* ln1b   = (const float*)d_in[17];
    const float* qkvw   = (const float*)d_in[18];
    const float* qkvbi  = (const float*)d_in[19];
    const float* aow    = (const float*)d_in[20];
    const float* aob    = (const float*)d_in[21];
    const float* ln2w   = (const float*)d_in[22];
    const float* ln2b   = (const float*)d_in[23];
    const float* ff1w   = (const float*)d_in[24];
    const float* ff1b   = (const float*)d_in[25];
    const float* ff2w   = (const float*)d_in[26];
    const float* ff2b   = (const float*)d_in[27];
    const float* Cwp    = (const float*)d_in[28];
    const float* powp   = (const float*)d_in[29];
    const float* Bwp    = (const float*)d_in[30];
    const float* piwp   = (const float*)d_in[31];

    // ---- workspace arena (byte cursor, 256B aligned) ----
    char* base = (char*)d_ws;
    size_t cur = 0;
    auto allocB = [&](size_t bytes) { char* p = base + cur; cur = (cur + bytes + 255) & ~(size_t)255; return p; };
    auto allocF = [&](size_t n) { return (float*)allocB(n * 4); };
    auto allocH = [&](size_t n) { return (ushort*)allocB(n * 2); };

    // fp32
    float* h     = allocF((size_t)kMtok * kD);
    float* xz    = allocF((size_t)kMtok * 2 * kDi);
    float* xc    = allocF((size_t)kMtok * kDi);
    float* bcb   = allocF((size_t)kMtok * 32);
    float* dlt   = allocF((size_t)kMtok * kDi);
    float* st    = allocF((size_t)kNL * kB * kDi * kN);
    float* x768  = allocF((size_t)kMref * kD);
    float* qkvB  = allocF((size_t)kMref * 3 * kD);
    float* d1536 = allocF((size_t)kMref * kDi);
    // bf16 activations
    ushort* xin_bf  = allocH((size_t)kMtok * kD);
    ushort* xc_bf   = allocH((size_t)kMtok * kDi);
    ushort* dtin_bf = allocH((size_t)kMtok * 64);
    ushort* yb_bf   = allocH((size_t)kMtok * kDi);
    ushort* dDi_bf  = allocH((size_t)128 * kDi);
    ushort* tb_bf   = allocH((size_t)128 * kD);
    ushort* o768_bf = allocH((size_t)128 * kD);
    ushort* f3_bf   = allocH((size_t)128 * 4 * kD);
    ushort* x768_bf = allocH((size_t)128 * kD);
    // bf16 weights (always resident)
    ushort* xpw_bf  = allocH((size_t)kNL * 128 * kDi);
    ushort* dpw_bf  = allocH((size_t)kNL * kDi * 64);
    ushort* powp_bf = allocH((size_t)kD * kDi);
    ushort* qkvw_bf = allocH((size_t)3 * kD * kD);
    ushort* aow_bf  = allocH((size_t)kD * kD);
    ushort* ff1w_bf = allocH((size_t)4 * kD * kD);
    ushort* ff2w_bf = allocH((size_t)kD * 4 * kD);
    ushort* piw_bf  = allocH((size_t)kDi * kD);
    ushort* emb_bf  = allocH((size_t)kVp * kD);

    // try full upfront conversion of ipw/opw; fallback to per-layer staging
    size_t base_end = cur;
    ushort* ipw_all = allocH((size_t)kNL * 2 * kDi * kD);
    ushort* opw_all = allocH((size_t)kNL * kD * kDi);
    bool full = (cur <= ws_size);
    ushort* ipw_stg = nullptr;
    ushort* opw_stg = nullptr;
    if (!full) {
        cur = base_end;
        ipw_stg = allocH((size_t)2 * kDi * kD);
        opw_stg = allocH((size_t)kD * kDi);
        if (cur > ws_size) return;  // even base does not fit -> loud failure
    }

    auto cvt = [&](const float* s, ushort* d, size_t n) {
        cvt_kernel<<<dim3((unsigned)((n / 4 + 255) / 256)), dim3(256), 0, stream>>>(s, d, (int)n);
    };

    hipMemsetAsync(st, 0, sizeof(float) * (size_t)kNL * kB * kDi * kN, stream);

    // ---- upfront weight conversions ----
    cvt_xpw_kernel<<<dim3(2880), dim3(256), 0, stream>>>(xpw, xpw_bf);
    cvt_dpw_kernel<<<dim3(9216), dim3(256), 0, stream>>>(dpw, dpw_bf);
    cvt(powp, powp_bf, (size_t)kD * kDi);
    cvt(qkvw, qkvw_bf, (size_t)3 * kD * kD);
    cvt(aow,  aow_bf,  (size_t)kD * kD);
    cvt(ff1w, ff1w_bf, (size_t)4 * kD * kD);
    cvt(ff2w, ff2w_bf, (size_t)kD * 4 * kD);
    cvt(piwp, piw_bf,  (size_t)kDi * kD);
    cvt(embed, emb_bf, (size_t)kV * kD);
    if (full) {
        cvt(ipw, ipw_all, (size_t)kNL * 2 * kDi * kD);
        cvt(opw, opw_all, (size_t)kNL * kD * kDi);
    }

    for (int pass = 0; pass < 2; ++pass) {
        const int* ids = pass ? a_ids : q_ids;
        const int* msk = pass ? a_msk : q_msk;

        embed_kernel<<<dim3(kMtok * kD / 256), dim3(256), 0, stream>>>(ids, msk, embed, h);

        for (int l = 0; l < kNL; ++l) {
            const ushort* ipw_l;
            const ushort* opw_l;
            if (full) {
                ipw_l = ipw_all + (size_t)l * 2 * kDi * kD;
                opw_l = opw_all + (size_t)l * kD * kDi;
            } else {
                cvt(ipw + (size_t)l * 2 * kDi * kD, ipw_stg, (size_t)2 * kDi * kD);
                cvt(opw + (size_t)l * kD * kDi, opw_stg, (size_t)kD * kDi);
                ipw_l = ipw_stg;
                opw_l = opw_stg;
            }
            rms_kernel<<<dim3(kMtok), dim3(256), 0, stream>>>(h, norm_w + (size_t)l * kD, xin_bf);
            gemm<128, 128, 0, 0, 0, 0>(xin_bf, kD, ipw_l, kD, xz, 2 * kDi, nullptr, 0,
                                       nullptr, kMtok, 2 * kDi, kD, stream);
            conv_kernel<<<dim3(kMtok * kDi / 256), dim3(256), 0, stream>>>(
                xz, cw + (size_t)l * kDi * kK, cb + (size_t)l * kDi, xc, xc_bf);
            gemm<64, 64, 0, 0, 0, 3>(xc_bf, kDi, xpw_bf + (size_t)l * 128 * kDi, kDi,
                                     bcb, 0, dtin_bf, 0, nullptr, kMtok, 128, kDi, stream);
            gemm<64, 64, 1, 1, 0, 0>(dtin_bf, 64, dpw_bf + (size_t)l * kDi * 64, 64, dlt, kDi,
                                     nullptr, 0, dpb + (size_t)l * kDi, kMtok, kDi, 64, stream);
            scan_kernel<<<dim3(kB * kDi * kN / 256), dim3(256), 0, stream>>>(
                dlt, xc, xz, bcb, alog + (size_t)l * kDi * kN, dpp + (size_t)l * kDi,
                st + (size_t)l * kB * kDi * kN, yb_bf);
            gemm<64, 64, 0, 0, 1, 0>(yb_bf, kDi, opw_l, kDi, h, kD, nullptr, 0,
                                     nullptr, kMtok, kD, kDi, stream);
        }

        if (pass == 0) {
            contract_kernel<<<dim3(kMref * kDi / 256), dim3(256), 0, stream>>>(st, Cwp, dDi_bf);
            for (int it = 0; it < 12; ++it) {
                gemm<128, 64, 0, 0, 0, 0>(dDi_bf, kDi, powp_bf, kDi, x768, kD, nullptr, 0,
                                          nullptr, kMref, kD, kDi, stream);
                ln_kernel<<<dim3(kMref), dim3(256), 0, stream>>>(x768, ln1w, ln1b, tb_bf);
                gemm<128, 64, 1, 0, 0, 0>(tb_bf, kD, qkvw_bf, kD, qkvB, 3 * kD, nullptr, 0,
                                          qkvbi, kMref, 3 * kD, kD, stream);
                attn_kernel<<<dim3(kB * kNH), dim3(32), 0, stream>>>(qkvB, o768_bf);
                gemm<128, 64, 1, 0, 1, 0>(o768_bf, kD, aow_bf, kD, x768, kD, nullptr, 0,
                                          aob, kMref, kD, kD, stream);
                ln_kernel<<<dim3(kMref), dim3(256), 0, stream>>>(x768, ln2w, ln2b, tb_bf);
                gemm<128, 64, 1, 2, 0, 2>(tb_bf, kD, ff1w_bf, kD, nullptr, 0, f3_bf, 4 * kD,
                                          ff1b, kMref, 4 * kD, kD, stream);
                gemm<128, 64, 1, 0, 1, 1>(f3_bf, 4 * kD, ff2w_bf, 4 * kD, x768, kD, x768_bf, kD,
                                          ff2b, kMref, kD, 4 * kD, stream);
                gemm<128, 64, 0, 0, 0, 0>(x768_bf, kD, piw_bf, kD, d1536, kDi, nullptr, 0,
                                          nullptr, kMref, kDi, kD, stream);
                update_contract_kernel<<<dim3(kMref * kDi / 256), dim3(256), 0, stream>>>(
                    d1536, Bwp, st, Cwp, dDi_bf);
            }
        } else {
            rms_kernel<<<dim3(kMtok), dim3(256), 0, stream>>>(h, norm_f, xin_bf);
            gemm<128, 128, 0, 0, 0, 0>(xin_bf, kD, emb_bf, kD, (float*)d_out, kV, nullptr, 0,
                                       nullptr, kMtok, kV, kD, stream);
        }
    }
}

// Round 5
// 9359.605 us; speedup vs baseline: 1.5166x; 1.5166x over previous
//
#include <hip/hip_runtime.h>
#include <math.h>

namespace {

constexpr int kNL = 24, kD = 768, kDi = 1536, kN = 16, kR = 48, kK = 4, kV = 50280, kNH = 12;
constexpr int kB = 4, kS = 256;
constexpr int kMtok = kB * kS;   // 1024 token rows
constexpr int kMref = kB * kNL;  // 96 refine rows
constexpr int kVp = 50304;       // kV padded to 128

using bf16x8 = __attribute__((ext_vector_type(8))) short;
using f32x4  = __attribute__((ext_vector_type(4))) float;

__device__ __forceinline__ float siluf(float x) { return x / (1.f + __expf(-x)); }

__device__ __forceinline__ ushort f2b(float f) {
    union { float f; unsigned u; } v; v.f = f;
    unsigned u = v.u;
    unsigned r = (u + 0x7FFFu + ((u >> 16) & 1u)) >> 16;
    return (ushort)r;
}

#define GLOAD_LDS(g, l) \
    __builtin_amdgcn_global_load_lds((const __attribute__((address_space(1))) void*)(g), \
                                     (__attribute__((address_space(3))) void*)(l), 16, 0, 0)

// ---------------- bf16 MFMA GEMM: C[M,N] = A[M,K] @ B[N,K]^T ----------------
// BK=64, double-buffered LDS, prefetch-then-compute, XOR-swizzled LDS.
// ACT: 0 none, 1 softplus, 2 gelu(exact).
// OUTMODE:
//  0 fp32 C (+RES)        1 fp32 C + bf16 Cbf      2 bf16 Cbf only
//  3 x_proj: gn<48 -> dt-in bf16 (Cbf, ld 64; cols 48..63 zeroed);
//            gn in [48,80) -> C2[(gn-48)*1024 + gm]  (bc^T fp32)
//  4 dt:     C2[gn*1024 + gm] = v                     (dlt^T fp32)
//  5 in_proj: gn<1536 -> C[gm*1536+gn] (x half fp32);
//             gn>=1536 -> C2[(gn-1536)*1024+gm] = silu(v)  (z^T fp32)
template <int BM, int BN, int BIAS, int ACT, int RES, int OUTMODE>
__global__ __launch_bounds__(256, ((BM + BN) <= 128 ? 4 : 2)) void gemm_bf16(
    const ushort* __restrict__ A, int lda,
    const ushort* __restrict__ B, int ldb,
    float* __restrict__ C, int ldc,
    ushort* __restrict__ Cbf, int ldcb,
    float* __restrict__ C2,
    const float* __restrict__ bias,
    int M, int N, int K)
{
    constexpr int ACH = BM / 32;
    constexpr int BCH = BN / 32;
    constexpr int MI  = BM / 32;
    constexpr int NJ  = BN / 32;

    __shared__ ushort As[2][BM * 64];
    __shared__ ushort Bs[2][BN * 64];

    const int tid  = threadIdx.x;
    const int lane = tid & 63;
    const int wave = tid >> 6;
    const int m0 = blockIdx.y * BM;
    const int n0 = blockIdx.x * BN;
    const int wr = (wave >> 1) * (BM / 2);
    const int wc = (wave & 1) * (BN / 2);

    f32x4 acc[MI][NJ];
#pragma unroll
    for (int i = 0; i < MI; ++i)
#pragma unroll
        for (int j = 0; j < NJ; ++j) acc[i][j] = f32x4{0.f, 0.f, 0.f, 0.f};

    const int srow = lane >> 3;
    const int scol = ((lane & 7) ^ srow) * 8;
    const ushort* gA[ACH];
    const ushort* gB[BCH];
#pragma unroll
    for (int g = 0; g < ACH; ++g)
        gA[g] = A + (size_t)(m0 + (g * 4 + wave) * 8 + srow) * lda + scol;
#pragma unroll
    for (int g = 0; g < BCH; ++g)
        gB[g] = B + (size_t)(n0 + (g * 4 + wave) * 8 + srow) * ldb + scol;

    const int frow = lane & 15;
    const int kh   = lane >> 4;
    const int nt   = K >> 6;

#pragma unroll
    for (int g = 0; g < ACH; ++g) GLOAD_LDS(gA[g], &As[0][(g * 4 + wave) * 512]);
#pragma unroll
    for (int g = 0; g < BCH; ++g) GLOAD_LDS(gB[g], &Bs[0][(g * 4 + wave) * 512]);
    __syncthreads();

    int cur = 0;
    for (int t = 0; t < nt; ++t) {
        if (t + 1 < nt) {
            const int off = (t + 1) * 64;
#pragma unroll
            for (int g = 0; g < ACH; ++g) GLOAD_LDS(gA[g] + off, &As[cur ^ 1][(g * 4 + wave) * 512]);
#pragma unroll
            for (int g = 0; g < BCH; ++g) GLOAD_LDS(gB[g] + off, &Bs[cur ^ 1][(g * 4 + wave) * 512]);
        }
#pragma unroll
        for (int s = 0; s < 2; ++s) {
            bf16x8 fa[MI], fb[NJ];
#pragma unroll
            for (int i = 0; i < MI; ++i) {
                int r = wr + i * 16 + frow;
                int slot = (s * 4 + kh) ^ (r & 7);
                fa[i] = *(const bf16x8*)&As[cur][r * 64 + slot * 8];
            }
#pragma unroll
            for (int j = 0; j < NJ; ++j) {
                int r = wc + j * 16 + frow;
                int slot = (s * 4 + kh) ^ (r & 7);
                fb[j] = *(const bf16x8*)&Bs[cur][r * 64 + slot * 8];
            }
#pragma unroll
            for (int i = 0; i < MI; ++i)
#pragma unroll
                for (int j = 0; j < NJ; ++j)
                    acc[i][j] = __builtin_amdgcn_mfma_f32_16x16x32_bf16(fa[i], fb[j], acc[i][j], 0, 0, 0);
        }
        __syncthreads();
        cur ^= 1;
    }

    const int ccol = lane & 15;
    const int crow = (lane >> 4) * 4;
#pragma unroll
    for (int i = 0; i < MI; ++i) {
#pragma unroll
        for (int j = 0; j < NJ; ++j) {
            int gn = n0 + wc + j * 16 + ccol;
            if (gn >= N) continue;
            float bv = BIAS ? bias[gn] : 0.f;
#pragma unroll
            for (int q = 0; q < 4; ++q) {
                int gm = m0 + wr + i * 16 + crow + q;
                if (gm >= M) continue;
                float v = acc[i][j][q] + bv;
                if (ACT == 1) v = fmaxf(v, 0.f) + log1pf(expf(-fabsf(v)));
                if (ACT == 2) v = 0.5f * v * (1.f + erff(v * 0.70710678118654752f));
                if (OUTMODE == 3) {
                    if (gn < 48) Cbf[(size_t)gm * 64 + gn] = f2b(v);
                    else if (gn < 64) { Cbf[(size_t)gm * 64 + gn] = 0; C2[(size_t)(gn - 48) * kMtok + gm] = v; }
                    else if (gn < 80) C2[(size_t)(gn - 48) * kMtok + gm] = v;
                } else if (OUTMODE == 4) {
                    C2[(size_t)gn * kMtok + gm] = v;
                } else if (OUTMODE == 5) {
                    if (gn < kDi) C[(size_t)gm * kDi + gn] = v;
                    else C2[(size_t)(gn - kDi) * kMtok + gm] = siluf(v);
                } else {
                    size_t ci = (size_t)gm * ldc + gn;
                    if (RES) v += C[ci];
                    if (OUTMODE != 2) C[ci] = v;
                    if (OUTMODE == 1 || OUTMODE == 2) Cbf[(size_t)gm * ldcb + gn] = f2b(v);
                }
            }
        }
    }
}

template <int BM, int BN, int BIAS, int ACT, int RES, int OUTMODE>
static void gemm(const ushort* A, int lda, const ushort* B, int ldb,
                 float* C, int ldc, ushort* Cb, int ldcb, float* C2,
                 const float* bias, int M, int N, int K, hipStream_t s)
{
    dim3 g((N + BN - 1) / BN, (M + BM - 1) / BM);
    gemm_bf16<BM, BN, BIAS, ACT, RES, OUTMODE><<<g, dim3(256), 0, s>>>(
        A, lda, B, ldb, C, ldc, Cb, ldcb, C2, bias, M, N, K);
}

// ---------------- conversions ----------------
__global__ void cvt_kernel(const float* __restrict__ src, ushort* __restrict__ dst, int n) {
    int i = (blockIdx.x * 256 + threadIdx.x) * 4;
    if (i >= n) return;
    float4 v = *(const float4*)(src + i);
    ushort4 o; o.x = f2b(v.x); o.y = f2b(v.y); o.z = f2b(v.z); o.w = f2b(v.w);
    *(ushort4*)(dst + i) = o;
}

// xpw [24][80][1536] -> padded [24][128][1536]
__global__ void cvt_xpw_kernel(const float* __restrict__ src, ushort* __restrict__ dst) {
    int i = (blockIdx.x * 256 + threadIdx.x) * 4;
    if (i >= 24 * 80 * 1536) return;
    int l = i / (80 * 1536), r = i - l * (80 * 1536);
    int row = r / 1536, col = r - row * 1536;
    float4 v = *(const float4*)(src + i);
    ushort4 o; o.x = f2b(v.x); o.y = f2b(v.y); o.z = f2b(v.z); o.w = f2b(v.w);
    *(ushort4*)(dst + ((size_t)(l * 128 + row)) * 1536 + col) = o;
}

// dpw [24][1536][48] -> padded [24][1536][64] (K-pad zero)
__global__ void cvt_dpw_kernel(const float* __restrict__ src, ushort* __restrict__ dst) {
    int i = blockIdx.x * 256 + threadIdx.x;
    if (i >= 24 * 1536 * 64) return;
    int col = i & 63, row = i >> 6;
    dst[i] = (col < 48) ? f2b(src[(size_t)row * 48 + col]) : (ushort)0;
}

// ---------------- embedding ----------------
__global__ void embed_kernel(const int* __restrict__ ids, const int* __restrict__ msk,
                             const float* __restrict__ embed, float* __restrict__ h)
{
    int i = blockIdx.x * 256 + threadIdx.x;
    int row = i / kD, col = i - row * kD;
    h[i] = embed[(size_t)ids[row] * kD + col] * (float)msk[row];
}

// ---------------- RMSNorm -> bf16 ----------------
__global__ __launch_bounds__(256) void rms_kernel(const float* __restrict__ x,
                                                  const float* __restrict__ w,
                                                  ushort* __restrict__ out)
{
    __shared__ float red[256];
    int row = blockIdx.x, tid = threadIdx.x;
    const float* xr = x + (size_t)row * kD;
    float s = 0.f;
    for (int j = tid; j < kD; j += 256) { float v = xr[j]; s += v * v; }
    red[tid] = s; __syncthreads();
    for (int o = 128; o > 0; o >>= 1) { if (tid < o) red[tid] += red[tid + o]; __syncthreads(); }
    float rs = rsqrtf(red[0] / (float)kD + 1e-5f);
    for (int j = tid; j < kD; j += 256) out[(size_t)row * kD + j] = f2b(xr[j] * rs * w[j]);
}

// ---------------- LayerNorm -> bf16 ----------------
__global__ __launch_bounds__(256) void ln_kernel(const float* __restrict__ x,
                                                 const float* __restrict__ w,
                                                 const float* __restrict__ b,
                                                 ushort* __restrict__ out)
{
    __shared__ float r1[256], r2[256];
    int row = blockIdx.x, tid = threadIdx.x;
    const float* xr = x + (size_t)row * kD;
    float s = 0.f, s2 = 0.f;
    for (int j = tid; j < kD; j += 256) { float v = xr[j]; s += v; s2 += v * v; }
    r1[tid] = s; r2[tid] = s2; __syncthreads();
    for (int o = 128; o > 0; o >>= 1) {
        if (tid < o) { r1[tid] += r1[tid + o]; r2[tid] += r2[tid + o]; }
        __syncthreads();
    }
    float mean = r1[0] / (float)kD;
    float var = r2[0] / (float)kD - mean * mean;
    float rs = rsqrtf(var + 1e-5f);
    for (int j = tid; j < kD; j += 256)
        out[(size_t)row * kD + j] = f2b((xr[j] - mean) * rs * w[j] + b[j]);
}

// ---------------- causal conv (K=4) + bias + silu ----------
// thread owns (d, 16 consecutive t) -> emits row-major bf16 AND xc^T fp32.
__global__ __launch_bounds__(256) void conv_kernel(
    const float* __restrict__ xbuf /*[1024][1536]*/, const float* __restrict__ cw,
    const float* __restrict__ cb, ushort* __restrict__ xc_bf /*[1024][1536]*/,
    float* __restrict__ xcT /*[1536][1024]*/)
{
    int d   = blockIdx.x * 256 + threadIdx.x;   // grid.x = kDi/256
    int bt0 = blockIdx.y * 16;                  // grid.y = kMtok/16 (tile within one b)
    int t0  = bt0 & (kS - 1);
    float w0 = cw[d * 4], w1 = cw[d * 4 + 1], w2 = cw[d * 4 + 2], w3 = cw[d * 4 + 3];
    float bias = cb[d];
    float xv[19];
#pragma unroll
    for (int j = 0; j < 19; ++j) {
        int tt = t0 - 3 + j;
        xv[j] = (tt >= 0) ? xbuf[(size_t)(bt0 - 3 + j) * kDi + d] : 0.f;
    }
    float out[16];
#pragma unroll
    for (int e = 0; e < 16; ++e) {
        float s = bias + xv[e] * w0 + xv[e + 1] * w1 + xv[e + 2] * w2 + xv[e + 3] * w3;
        float v = siluf(s);
        out[e] = v;
        xc_bf[(size_t)(bt0 + e) * kDi + d] = f2b(v);
    }
    float4* dst = (float4*)(xcT + (size_t)d * kMtok + bt0);
#pragma unroll
    for (int i = 0; i < 4; ++i)
        dst[i] = make_float4(out[i * 4], out[i * 4 + 1], out[i * 4 + 2], out[i * 4 + 3]);
}

// ---------------- selective scan + gating (t-contiguous, float4 groups) ----
__global__ __launch_bounds__(256) void scan_kernel(
    const float* __restrict__ dltT, const float* __restrict__ xcT,
    const float* __restrict__ zT, const float* __restrict__ bcT,
    const float* __restrict__ alog, const float* __restrict__ dp,
    float* __restrict__ states, ushort* __restrict__ y)
{
    int gid = blockIdx.x * 256 + threadIdx.x;    // kB*kDi*kN threads
    int n = gid & 15;
    int d = (gid >> 4) % kDi;
    int b = gid / (kDi * kN);
    float Areg = -__expf(alog[d * kN + n]);
    float dpv = dp[d];
    size_t sidx = (size_t)(b * kDi + d) * kN + n;
    float hs = states[sidx];
    const float4* pD = (const float4*)(dltT + (size_t)d * kMtok + b * kS);
    const float4* pX = (const float4*)(xcT  + (size_t)d * kMtok + b * kS);
    const float4* pZ = (const float4*)(zT   + (size_t)d * kMtok + b * kS);
    const float4* pB = (const float4*)(bcT + (size_t)n * kMtok + b * kS);
    const float4* pC = (const float4*)(bcT + (size_t)(16 + n) * kMtok + b * kS);
    float4 D = pD[0], X = pX[0], Z = pZ[0], Bq = pB[0], Cq = pC[0];
    ushort* yrow = y + (size_t)(b * kS) * kDi + d;
    for (int g = 0; g < kS / 4; ++g) {
        float4 Dn, Xn, Zn, Bn, Cn;
        if (g + 1 < kS / 4) { Dn = pD[g + 1]; Xn = pX[g + 1]; Zn = pZ[g + 1]; Bn = pB[g + 1]; Cn = pC[g + 1]; }
#pragma unroll
        for (int e = 0; e < 4; ++e) {
            float dv = (&D.x)[e], xv = (&X.x)[e], zv = (&Z.x)[e];
            float Bv = (&Bq.x)[e], Cv = (&Cq.x)[e];
            hs = __expf(dv * Areg) * hs + (dv * xv) * Bv;
            float p = hs * Cv;
            p += __shfl_xor(p, 1, 16);
            p += __shfl_xor(p, 2, 16);
            p += __shfl_xor(p, 4, 16);
            p += __shfl_xor(p, 8, 16);
            if (n == 0) yrow[(size_t)(g * 4 + e) * kDi] = f2b((p + xv * dpv) * zv);
        }
        D = Dn; X = Xn; Z = Zn; Bq = Bn; Cq = Cn;
    }
    states[sidx] = hs;
}

// ---------------- refine: d = states . C_w -> bf16 [row, di] --------------
__global__ void contract_kernel(const float* __restrict__ st, const float* __restrict__ Cw,
                                ushort* __restrict__ dDi)
{
    int i = blockIdx.x * 256 + threadIdx.x;      // kMref * kDi
    int row = i / kDi, di = i - row * kDi;
    int b = row / kNL, s = row - b * kNL;
    const float* sp = st + ((size_t)(s * kB + b) * kDi + di) * kN;
    float acc = 0.f;
#pragma unroll
    for (int nn = 0; nn < kN; ++nn) acc += sp[nn] * Cw[nn];
    dDi[i] = f2b(acc);
}

// ---------------- refine: states += d1536*B_w, then dDi = states . C_w ----
__global__ void update_contract_kernel(const float* __restrict__ d1536,
                                       const float* __restrict__ Bw,
                                       float* __restrict__ st,
                                       const float* __restrict__ Cw,
                                       ushort* __restrict__ dDi)
{
    int i = blockIdx.x * 256 + threadIdx.x;      // kMref * kDi
    int row = i / kDi, di = i - row * kDi;
    int b = row / kNL, s = row - b * kNL;
    float dv = d1536[i];
    float* sp = st + ((size_t)(s * kB + b) * kDi + di) * kN;
    float acc = 0.f;
#pragma unroll
    for (int nn = 0; nn < kN; ++nn) {
        float v = sp[nn] + dv * Bw[nn];
        sp[nn] = v;
        acc += v * Cw[nn];
    }
    dDi[i] = f2b(acc);
}

// ---------------- tiny attention (B=4, S=24, 12 heads, hd=64) -> bf16 -----
__global__ __launch_bounds__(32) void attn_kernel(const float* __restrict__ qkv,
                                                  ushort* __restrict__ o)
{
    int b = blockIdx.x / kNH;
    int hh = blockIdx.x - b * kNH;
    int sq = threadIdx.x;
    if (sq >= kNL) return;
    const float* qrow = qkv + (size_t)(b * kNL + sq) * (3 * kD) + hh * 64;
    float q[64];
#pragma unroll
    for (int e = 0; e < 64; ++e) q[e] = qrow[e];
    float sc[kNL];
    float mx = -1e30f;
    for (int sk = 0; sk < kNL; ++sk) {
        const float* krow = qkv + (size_t)(b * kNL + sk) * (3 * kD) + kD + hh * 64;
        float dt = 0.f;
#pragma unroll
        for (int e = 0; e < 64; ++e) dt += q[e] * krow[e];
        dt *= 0.125f;
        sc[sk] = dt;
        mx = fmaxf(mx, dt);
    }
    float sum = 0.f;
    for (int sk = 0; sk < kNL; ++sk) { sc[sk] = expf(sc[sk] - mx); sum += sc[sk]; }
    float inv = 1.f / sum;
    float out[64];
#pragma unroll
    for (int e = 0; e < 64; ++e) out[e] = 0.f;
    for (int sk = 0; sk < kNL; ++sk) {
        float wgt = sc[sk] * inv;
        const float* vrow = qkv + (size_t)(b * kNL + sk) * (3 * kD) + 2 * kD + hh * 64;
#pragma unroll
        for (int e = 0; e < 64; ++e) out[e] += wgt * vrow[e];
    }
    ushort* orow = o + (size_t)(b * kNL + sq) * kD + hh * 64;
#pragma unroll
    for (int e = 0; e < 64; ++e) orow[e] = f2b(out[e]);
}

} // namespace

extern "C" void kernel_launch(void* const* d_in, const int* in_sizes, int n_in,
                              void* d_out, int out_size, void* d_ws, size_t ws_size,
                              hipStream_t stream)
{
    const int*   q_ids  = (const int*)d_in[0];
    const int*   q_msk  = (const int*)d_in[1];
    const int*   a_ids  = (const int*)d_in[2];
    const int*   a_msk  = (const int*)d_in[3];
    const float* embed  = (const float*)d_in[4];
    const float* norm_w = (const float*)d_in[5];
    const float* ipw    = (const float*)d_in[6];
    const float* cw     = (const float*)d_in[7];
    const float* cb     = (const float*)d_in[8];
    const float* xpw    = (const float*)d_in[9];
    const float* dpw    = (const float*)d_in[10];
    const float* dpb    = (const float*)d_in[11];
    const float* alog   = (const float*)d_in[12];
    const float* dpp    = (const float*)d_in[13];
    const float* opw    = (const float*)d_in[14];
    const float* norm_f = (const float*)d_in[15];
    const float* ln1w   = (const float*)d_in[16];
    const float* ln1b   = (const float*)d_in[17];
    const float* qkvw   = (const float*)d_in[18];
    const float* qkvbi  = (const float*)d_in[19];
    const float* aow    = (const float*)d_in[20];
    const float* aob    = (const float*)d_in[21];
    const float* ln2w   = (const float*)d_in[22];
    const float* ln2b   = (const float*)d_in[23];
    const float* ff1w   = (const float*)d_in[24];
    const float* ff1b   = (const float*)d_in[25];
    const float* ff2w   = (const float*)d_in[26];
    const float* ff2b   = (const float*)d_in[27];
    const float* Cwp    = (const float*)d_in[28];
    const float* powp   = (const float*)d_in[29];
    const float* Bwp    = (const float*)d_in[30];
    const float* piwp   = (const float*)d_in[31];

    // ---- workspace arena ----
    char* base = (char*)d_ws;
    size_t cur = 0;
    auto allocB = [&](size_t bytes) { char* p = base + cur; cur = (cur + bytes + 255) & ~(size_t)255; return p; };
    auto allocF = [&](size_t n) { return (float*)allocB(n * 4); };
    auto allocH = [&](size_t n) { return (ushort*)allocB(n * 2); };

    // fp32
    float* h     = allocF((size_t)kMtok * kD);
    float* xbuf  = allocF((size_t)kMtok * kDi);     // in_proj x half, [t][d]
    float* zT    = allocF((size_t)kDi * kMtok);     // silu(z) transposed
    float* xcT   = allocF((size_t)kDi * kMtok);     // conv out transposed
    float* bcT   = allocF((size_t)32 * kMtok);      // B/C transposed [32][1024]
    float* dltT  = allocF((size_t)kDi * kMtok);     // delta transposed
    float* st    = allocF((size_t)kNL * kB * kDi * kN);
    float* x768  = allocF((size_t)kMref * kD);
    float* qkvB  = allocF((size_t)kMref * 3 * kD);
    float* d1536 = allocF((size_t)kMref * kDi);
    // bf16 activations
    ushort* xin_bf  = allocH((size_t)kMtok * kD);
    ushort* xc_bf   = allocH((size_t)kMtok * kDi);
    ushort* dtin_bf = allocH((size_t)kMtok * 64);
    ushort* yb_bf   = allocH((size_t)kMtok * kDi);
    ushort* dDi_bf  = allocH((size_t)128 * kDi);
    ushort* tb_bf   = allocH((size_t)128 * kD);
    ushort* o768_bf = allocH((size_t)128 * kD);
    ushort* f3_bf   = allocH((size_t)128 * 4 * kD);
    ushort* x768_bf = allocH((size_t)128 * kD);
    // bf16 weights
    ushort* xpw_bf  = allocH((size_t)kNL * 128 * kDi);
    ushort* dpw_bf  = allocH((size_t)kNL * kDi * 64);
    ushort* powp_bf = allocH((size_t)kD * kDi);
    ushort* qkvw_bf = allocH((size_t)3 * kD * kD);
    ushort* aow_bf  = allocH((size_t)kD * kD);
    ushort* ff1w_bf = allocH((size_t)4 * kD * kD);
    ushort* ff2w_bf = allocH((size_t)kD * 4 * kD);
    ushort* piw_bf  = allocH((size_t)kDi * kD);
    ushort* emb_bf  = allocH((size_t)kVp * kD);

    size_t base_end = cur;
    ushort* ipw_all = allocH((size_t)kNL * 2 * kDi * kD);
    ushort* opw_all = allocH((size_t)kNL * kD * kDi);
    bool full = (cur <= ws_size);
    ushort* ipw_stg = nullptr;
    ushort* opw_stg = nullptr;
    if (!full) {
        cur = base_end;
        ipw_stg = allocH((size_t)2 * kDi * kD);
        opw_stg = allocH((size_t)kD * kDi);
        if (cur > ws_size) return;
    }

    auto cvt = [&](const float* s, ushort* d, size_t n) {
        cvt_kernel<<<dim3((unsigned)((n / 4 + 255) / 256)), dim3(256), 0, stream>>>(s, d, (int)n);
    };

    hipMemsetAsync(st, 0, sizeof(float) * (size_t)kNL * kB * kDi * kN, stream);

    cvt_xpw_kernel<<<dim3(2880), dim3(256), 0, stream>>>(xpw, xpw_bf);
    cvt_dpw_kernel<<<dim3(9216), dim3(256), 0, stream>>>(dpw, dpw_bf);
    cvt(powp, powp_bf, (size_t)kD * kDi);
    cvt(qkvw, qkvw_bf, (size_t)3 * kD * kD);
    cvt(aow,  aow_bf,  (size_t)kD * kD);
    cvt(ff1w, ff1w_bf, (size_t)4 * kD * kD);
    cvt(ff2w, ff2w_bf, (size_t)kD * 4 * kD);
    cvt(piwp, piw_bf,  (size_t)kDi * kD);
    cvt(embed, emb_bf, (size_t)kV * kD);
    if (full) {
        cvt(ipw, ipw_all, (size_t)kNL * 2 * kDi * kD);
        cvt(opw, opw_all, (size_t)kNL * kD * kDi);
    }

    for (int pass = 0; pass < 2; ++pass) {
        const int* ids = pass ? a_ids : q_ids;
        const int* msk = pass ? a_msk : q_msk;

        embed_kernel<<<dim3(kMtok * kD / 256), dim3(256), 0, stream>>>(ids, msk, embed, h);

        for (int l = 0; l < kNL; ++l) {
            const ushort* ipw_l;
            const ushort* opw_l;
            if (full) {
                ipw_l = ipw_all + (size_t)l * 2 * kDi * kD;
                opw_l = opw_all + (size_t)l * kD * kDi;
            } else {
                cvt(ipw + (size_t)l * 2 * kDi * kD, ipw_stg, (size_t)2 * kDi * kD);
                cvt(opw + (size_t)l * kD * kDi, opw_stg, (size_t)kD * kDi);
                ipw_l = ipw_stg;
                opw_l = opw_stg;
            }
            rms_kernel<<<dim3(kMtok), dim3(256), 0, stream>>>(h, norm_w + (size_t)l * kD, xin_bf);
            gemm<128, 128, 0, 0, 0, 5>(xin_bf, kD, ipw_l, kD, xbuf, kDi, nullptr, 0, zT,
                                       nullptr, kMtok, 2 * kDi, kD, stream);
            conv_kernel<<<dim3(kDi / 256, kMtok / 16), dim3(256), 0, stream>>>(
                xbuf, cw + (size_t)l * kDi * kK, cb + (size_t)l * kDi, xc_bf, xcT);
            gemm<64, 64, 0, 0, 0, 3>(xc_bf, kDi, xpw_bf + (size_t)l * 128 * kDi, kDi,
                                     nullptr, 0, dtin_bf, 0, bcT, nullptr, kMtok, 128, kDi, stream);
            gemm<64, 64, 1, 1, 0, 4>(dtin_bf, 64, dpw_bf + (size_t)l * kDi * 64, 64,
                                     nullptr, 0, nullptr, 0, dltT,
                                     dpb + (size_t)l * kDi, kMtok, kDi, 64, stream);
            scan_kernel<<<dim3(kB * kDi * kN / 256), dim3(256), 0, stream>>>(
                dltT, xcT, zT, bcT, alog + (size_t)l * kDi * kN, dpp + (size_t)l * kDi,
                st + (size_t)l * kB * kDi * kN, yb_bf);
            gemm<64, 64, 0, 0, 1, 0>(yb_bf, kDi, opw_l, kDi, h, kD, nullptr, 0, nullptr,
                                     nullptr, kMtok, kD, kDi, stream);
        }

        if (pass == 0) {
            contract_kernel<<<dim3(kMref * kDi / 256), dim3(256), 0, stream>>>(st, Cwp, dDi_bf);
            for (int it = 0; it < 12; ++it) {
                gemm<64, 64, 0, 0, 0, 0>(dDi_bf, kDi, powp_bf, kDi, x768, kD, nullptr, 0, nullptr,
                                         nullptr, kMref, kD, kDi, stream);
                ln_kernel<<<dim3(kMref), dim3(256), 0, stream>>>(x768, ln1w, ln1b, tb_bf);
                gemm<64, 64, 1, 0, 0, 0>(tb_bf, kD, qkvw_bf, kD, qkvB, 3 * kD, nullptr, 0, nullptr,
                                         qkvbi, kMref, 3 * kD, kD, stream);
                attn_kernel<<<dim3(kB * kNH), dim3(32), 0, stream>>>(qkvB, o768_bf);
                gemm<64, 64, 1, 0, 1, 0>(o768_bf, kD, aow_bf, kD, x768, kD, nullptr, 0, nullptr,
                                         aob, kMref, kD, kD, stream);
                ln_kernel<<<dim3(kMref), dim3(256), 0, stream>>>(x768, ln2w, ln2b, tb_bf);
                gemm<64, 64, 1, 2, 0, 2>(tb_bf, kD, ff1w_bf, kD, nullptr, 0, f3_bf, 4 * kD, nullptr,
                                         ff1b, kMref, 4 * kD, kD, stream);
                gemm<64, 64, 1, 0, 1, 1>(f3_bf, 4 * kD, ff2w_bf, 4 * kD, x768, kD, x768_bf, kD, nullptr,
                                         ff2b, kMref, kD, 4 * kD, stream);
                gemm<64, 64, 0, 0, 0, 0>(x768_bf, kD, piw_bf, kD, d1536, kDi, nullptr, 0, nullptr,
                                         nullptr, kMref, kDi, kD, stream);
                update_contract_kernel<<<dim3(kMref * kDi / 256), dim3(256), 0, stream>>>(
                    d1536, Bwp, st, Cwp, dDi_bf);
            }
        } else {
            rms_kernel<<<dim3(kMtok), dim3(256), 0, stream>>>(h, norm_f, xin_bf);
            gemm<128, 128, 0, 0, 0, 0>(xin_bf, kD, emb_bf, kD, (float*)d_out, kV, nullptr, 0, nullptr,
                                       nullptr, kMtok, kV, kD, stream);
        }
    }
}

// Round 6
// 9255.199 us; speedup vs baseline: 1.5337x; 1.0113x over previous
//
#include <hip/hip_runtime.h>
#include <math.h>

namespace {

constexpr int kNL = 24, kD = 768, kDi = 1536, kN = 16, kR = 48, kK = 4, kV = 50280, kNH = 12;
constexpr int kB = 4, kS = 256;
constexpr int kMtok = kB * kS;   // 1024 token rows
constexpr int kMref = kB * kNL;  // 96 refine rows
constexpr int kVp = 50304;       // kV padded to 128
constexpr int kNx = 1568;        // merged x_proj output cols (32 bc + 1536 delta)
constexpr int kNxPad = 1600;     // padded to 64

using bf16x8 = __attribute__((ext_vector_type(8))) short;
using f32x4  = __attribute__((ext_vector_type(4))) float;

__device__ __forceinline__ float siluf(float x) { return x / (1.f + __expf(-x)); }

__device__ __forceinline__ ushort f2b(float f) {
    union { float f; unsigned u; } v; v.f = f;
    unsigned u = v.u;
    unsigned r = (u + 0x7FFFu + ((u >> 16) & 1u)) >> 16;
    return (ushort)r;
}

#define GLOAD_LDS(g, l) \
    __builtin_amdgcn_global_load_lds((const __attribute__((address_space(1))) void*)(g), \
                                     (__attribute__((address_space(3))) void*)(l), 16, 0, 0)

// ---------------- bf16 MFMA GEMM: C[M,N] = A[M,K] @ B[N,K]^T ----------------
// PIPE=3: 3-buffer LDS, counted vmcnt + raw s_barrier (tile t+1 stays in
//         flight across the barrier; stage t+2 after it).
// PIPE=2: classic 2-buffer with __syncthreads (for the big logits grid).
// XOR-swizzled LDS both paths (pre-swizzled global source + swizzled ds_read).
// ACT: 0 none, 1 softplus, 2 gelu(exact).
// OUTMODE:
//  0 fp32 C (+RES)     1 fp32 C + bf16 Cbf     2 bf16 Cbf only
//  5 in_proj: gn<1536 -> C[gm*1536+gn] (x half fp32); gn>=1536 ->
//             C2[(gn-1536)*1024+gm] = silu(v)   (z^T fp32)
//  6 merged x_proj: gn<32 -> C2[gn*1024+gm] (bc^T); gn in [32,1568) ->
//             C[(gn-32)*1024+gm] = softplus(v + bias[gn-32])  (dlt^T)
//  7 pi + state update: st (C2) += v*bias[nn]; dDi (Cbf) = dot(st, aux)
template <int BM, int BN, int BIAS, int ACT, int RES, int OUTMODE, int PIPE>
__global__ __launch_bounds__(256, (PIPE == 3 ? 3 : 2)) void gemm_bf16(
    const ushort* __restrict__ A, int lda,
    const ushort* __restrict__ B, int ldb,
    float* __restrict__ C, int ldc,
    ushort* __restrict__ Cbf, int ldcb,
    float* __restrict__ C2,
    const float* __restrict__ bias,
    const float* __restrict__ aux,
    int M, int N, int K)
{
    constexpr int ACH = BM / 32;   // global_load_lds per wave per tile (A)
    constexpr int BCH = BN / 32;
    constexpr int MI  = BM / 32;
    constexpr int NJ  = BN / 32;

    __shared__ ushort As[PIPE][BM * 64];
    __shared__ ushort Bs[PIPE][BN * 64];

    const int tid  = threadIdx.x;
    const int lane = tid & 63;
    const int wave = tid >> 6;
    const int m0 = blockIdx.y * BM;
    const int n0 = blockIdx.x * BN;
    const int wr = (wave >> 1) * (BM / 2);
    const int wc = (wave & 1) * (BN / 2);

    f32x4 acc[MI][NJ];
#pragma unroll
    for (int i = 0; i < MI; ++i)
#pragma unroll
        for (int j = 0; j < NJ; ++j) acc[i][j] = f32x4{0.f, 0.f, 0.f, 0.f};

    const int srow = lane >> 3;
    const int scol = ((lane & 7) ^ srow) * 8;
    const ushort* gA[ACH];
    const ushort* gB[BCH];
#pragma unroll
    for (int g = 0; g < ACH; ++g)
        gA[g] = A + (size_t)(m0 + (g * 4 + wave) * 8 + srow) * lda + scol;
#pragma unroll
    for (int g = 0; g < BCH; ++g)
        gB[g] = B + (size_t)(n0 + (g * 4 + wave) * 8 + srow) * ldb + scol;

    const int frow = lane & 15;
    const int kh   = lane >> 4;
    const int nt   = K >> 6;

    auto stage = [&](int t, int buf) {
        const int off = t * 64;
#pragma unroll
        for (int g = 0; g < ACH; ++g) GLOAD_LDS(gA[g] + off, &As[buf][(g * 4 + wave) * 512]);
#pragma unroll
        for (int g = 0; g < BCH; ++g) GLOAD_LDS(gB[g] + off, &Bs[buf][(g * 4 + wave) * 512]);
    };
    auto compute = [&](int buf) {
#pragma unroll
        for (int s = 0; s < 2; ++s) {
            bf16x8 fa[MI], fb[NJ];
#pragma unroll
            for (int i = 0; i < MI; ++i) {
                int r = wr + i * 16 + frow;
                int slot = (s * 4 + kh) ^ (r & 7);
                fa[i] = *(const bf16x8*)&As[buf][r * 64 + slot * 8];
            }
#pragma unroll
            for (int j = 0; j < NJ; ++j) {
                int r = wc + j * 16 + frow;
                int slot = (s * 4 + kh) ^ (r & 7);
                fb[j] = *(const bf16x8*)&Bs[buf][r * 64 + slot * 8];
            }
#pragma unroll
            for (int i = 0; i < MI; ++i)
#pragma unroll
                for (int j = 0; j < NJ; ++j)
                    acc[i][j] = __builtin_amdgcn_mfma_f32_16x16x32_bf16(fa[i], fb[j], acc[i][j], 0, 0, 0);
        }
    };

    if constexpr (PIPE == 3) {
        stage(0, 0);
        if (nt > 1) stage(1, 1);
        for (int t = 0; t < nt; ++t) {
            if (t < nt - 1) {
                asm volatile("s_waitcnt vmcnt(%0)" :: "n"(ACH + BCH) : "memory");
            } else {
                asm volatile("s_waitcnt vmcnt(0)" ::: "memory");
            }
            __builtin_amdgcn_s_barrier();
            if (t + 2 < nt) stage(t + 2, (t + 2) % 3);
            compute(t % 3);
        }
        __builtin_amdgcn_s_barrier();
    } else {
        stage(0, 0);
        __syncthreads();
        int cur = 0;
        for (int t = 0; t < nt; ++t) {
            if (t + 1 < nt) stage(t + 1, cur ^ 1);
            compute(cur);
            __syncthreads();
            cur ^= 1;
        }
    }

    // epilogue: C/D layout col = lane&15, row = (lane>>4)*4 + q
    const int ccol = lane & 15;
    const int crow = (lane >> 4) * 4;
#pragma unroll
    for (int i = 0; i < MI; ++i) {
#pragma unroll
        for (int j = 0; j < NJ; ++j) {
            int gn = n0 + wc + j * 16 + ccol;
            if (gn >= N) continue;
            float bv = BIAS ? bias[gn] : 0.f;
#pragma unroll
            for (int q = 0; q < 4; ++q) {
                int gm = m0 + wr + i * 16 + crow + q;
                if (gm >= M) continue;
                float v = acc[i][j][q] + bv;
                if (ACT == 1) v = fmaxf(v, 0.f) + log1pf(expf(-fabsf(v)));
                if (ACT == 2) v = 0.5f * v * (1.f + erff(v * 0.70710678118654752f));
                if (OUTMODE == 5) {
                    if (gn < kDi) C[(size_t)gm * kDi + gn] = v;
                    else C2[(size_t)(gn - kDi) * kMtok + gm] = siluf(v);
                } else if (OUTMODE == 6) {
                    if (gn < 32) C2[(size_t)gn * kMtok + gm] = v;
                    else {
                        float w = v + bias[gn - 32];
                        w = fmaxf(w, 0.f) + log1pf(expf(-fabsf(w)));
                        C[(size_t)(gn - 32) * kMtok + gm] = w;
                    }
                } else if (OUTMODE == 7) {
                    int bb = gm / kNL, ss = gm - bb * kNL;
                    float* stp = C2 + ((size_t)(ss * kB + bb) * kDi + gn) * kN;
                    float a2 = 0.f;
#pragma unroll
                    for (int nn = 0; nn < kN; ++nn) {
                        float sv = stp[nn] + v * bias[nn];
                        stp[nn] = sv;
                        a2 += sv * aux[nn];
                    }
                    Cbf[(size_t)gm * ldcb + gn] = f2b(a2);
                } else {
                    size_t ci = (size_t)gm * ldc + gn;
                    if (RES) v += C[ci];
                    if (OUTMODE != 2) C[ci] = v;
                    if (OUTMODE == 1 || OUTMODE == 2) Cbf[(size_t)gm * ldcb + gn] = f2b(v);
                }
            }
        }
    }
}

template <int BM, int BN, int BIAS, int ACT, int RES, int OUTMODE, int PIPE>
static void gemm(const ushort* A, int lda, const ushort* B, int ldb,
                 float* C, int ldc, ushort* Cb, int ldcb, float* C2,
                 const float* bias, const float* aux, int M, int N, int K, hipStream_t s)
{
    dim3 g((N + BN - 1) / BN, (M + BM - 1) / BM);
    gemm_bf16<BM, BN, BIAS, ACT, RES, OUTMODE, PIPE><<<g, dim3(256), 0, s>>>(
        A, lda, B, ldb, C, ldc, Cb, ldcb, C2, bias, aux, M, N, K);
}

// ---------------- conversions ----------------
__global__ void cvt_kernel(const float* __restrict__ src, ushort* __restrict__ dst, int n) {
    int i = (blockIdx.x * 256 + threadIdx.x) * 4;
    if (i >= n) return;
    float4 v = *(const float4*)(src + i);
    ushort4 o; o.x = f2b(v.x); o.y = f2b(v.y); o.z = f2b(v.z); o.w = f2b(v.w);
    *(ushort4*)(dst + i) = o;
}

// dpw [24][1536][48] -> padded [24][1536][64] (K-pad zero)
__global__ void cvt_dpw_kernel(const float* __restrict__ src, ushort* __restrict__ dst) {
    int i = blockIdx.x * 256 + threadIdx.x;
    if (i >= 24 * 1536 * 64) return;
    int col = i & 63, row = i >> 6;
    dst[i] = (col < 48) ? f2b(src[(size_t)row * 48 + col]) : (ushort)0;
}

// xpw_dt^T: [24][1536][64]; dst[l][j][r] = bf16(xpw[l][r][j]) for r<48 else 0
__global__ void cvt_xpwdtT_kernel(const float* __restrict__ src, ushort* __restrict__ dst) {
    int i = blockIdx.x * 256 + threadIdx.x;
    if (i >= 24 * 1536 * 64) return;
    int r = i & 63;
    int j = (i >> 6) % 1536;
    int l = i / (1536 * 64);
    dst[i] = (r < 48) ? f2b(src[((size_t)l * 80 + r) * 1536 + j]) : (ushort)0;
}

// bc rows of merged B: xpw2[l][gn][k] = bf16(xpw[l][48+gn][k]), gn<32
__global__ void cvt_bc_kernel(const float* __restrict__ src, ushort* __restrict__ dst) {
    int i = blockIdx.x * 256 + threadIdx.x;
    if (i >= 24 * 32 * 1536) return;
    int k = i % 1536;
    int gn = (i / 1536) % 32;
    int l = i / (32 * 1536);
    dst[((size_t)l * kNxPad + gn) * 1536 + k] = f2b(src[((size_t)l * 80 + 48 + gn) * 1536 + k]);
}

// ---------------- embedding ----------------
__global__ void embed_kernel(const int* __restrict__ ids, const int* __restrict__ msk,
                             const float* __restrict__ embed, float* __restrict__ h)
{
    int i = blockIdx.x * 256 + threadIdx.x;
    int row = i / kD, col = i - row * kD;
    h[i] = embed[(size_t)ids[row] * kD + col] * (float)msk[row];
}

// ---------------- RMSNorm -> bf16 ----------------
__global__ __launch_bounds__(256) void rms_kernel(const float* __restrict__ x,
                                                  const float* __restrict__ w,
                                                  ushort* __restrict__ out)
{
    __shared__ float red[256];
    int row = blockIdx.x, tid = threadIdx.x;
    const float* xr = x + (size_t)row * kD;
    float s = 0.f;
    for (int j = tid; j < kD; j += 256) { float v = xr[j]; s += v * v; }
    red[tid] = s; __syncthreads();
    for (int o = 128; o > 0; o >>= 1) { if (tid < o) red[tid] += red[tid + o]; __syncthreads(); }
    float rs = rsqrtf(red[0] / (float)kD + 1e-5f);
    for (int j = tid; j < kD; j += 256) out[(size_t)row * kD + j] = f2b(xr[j] * rs * w[j]);
}

// ---------------- LayerNorm -> bf16 ----------------
__global__ __launch_bounds__(256) void ln_kernel(const float* __restrict__ x,
                                                 const float* __restrict__ w,
                                                 const float* __restrict__ b,
                                                 ushort* __restrict__ out)
{
    __shared__ float r1[256], r2[256];
    int row = blockIdx.x, tid = threadIdx.x;
    const float* xr = x + (size_t)row * kD;
    float s = 0.f, s2 = 0.f;
    for (int j = tid; j < kD; j += 256) { float v = xr[j]; s += v; s2 += v * v; }
    r1[tid] = s; r2[tid] = s2; __syncthreads();
    for (int o = 128; o > 0; o >>= 1) {
        if (tid < o) { r1[tid] += r1[tid + o]; r2[tid] += r2[tid + o]; }
        __syncthreads();
    }
    float mean = r1[0] / (float)kD;
    float var = r2[0] / (float)kD - mean * mean;
    float rs = rsqrtf(var + 1e-5f);
    for (int j = tid; j < kD; j += 256)
        out[(size_t)row * kD + j] = f2b((xr[j] - mean) * rs * w[j] + b[j]);
}

// ---------------- causal conv (K=4) + bias + silu ----------
__global__ __launch_bounds__(256) void conv_kernel(
    const float* __restrict__ xbuf, const float* __restrict__ cw,
    const float* __restrict__ cb, ushort* __restrict__ xc_bf,
    float* __restrict__ xcT)
{
    int d   = blockIdx.x * 256 + threadIdx.x;
    int bt0 = blockIdx.y * 16;
    int t0  = bt0 & (kS - 1);
    float w0 = cw[d * 4], w1 = cw[d * 4 + 1], w2 = cw[d * 4 + 2], w3 = cw[d * 4 + 3];
    float bias = cb[d];
    float xv[19];
#pragma unroll
    for (int j = 0; j < 19; ++j) {
        int tt = t0 - 3 + j;
        xv[j] = (tt >= 0) ? xbuf[(size_t)(bt0 - 3 + j) * kDi + d] : 0.f;
    }
    float out[16];
#pragma unroll
    for (int e = 0; e < 16; ++e) {
        float s = bias + xv[e] * w0 + xv[e + 1] * w1 + xv[e + 2] * w2 + xv[e + 3] * w3;
        float v = siluf(s);
        out[e] = v;
        xc_bf[(size_t)(bt0 + e) * kDi + d] = f2b(v);
    }
    float4* dst = (float4*)(xcT + (size_t)d * kMtok + bt0);
#pragma unroll
    for (int i = 0; i < 4; ++i)
        dst[i] = make_float4(out[i * 4], out[i * 4 + 1], out[i * 4 + 2], out[i * 4 + 3]);
}

// ---------------- selective scan + gating (t-contiguous) ----
__global__ __launch_bounds__(256) void scan_kernel(
    const float* __restrict__ dltT, const float* __restrict__ xcT,
    const float* __restrict__ zT, const float* __restrict__ bcT,
    const float* __restrict__ alog, const float* __restrict__ dp,
    float* __restrict__ states, ushort* __restrict__ y)
{
    int gid = blockIdx.x * 256 + threadIdx.x;
    int n = gid & 15;
    int d = (gid >> 4) % kDi;
    int b = gid / (kDi * kN);
    float Areg = -__expf(alog[d * kN + n]);
    float dpv = dp[d];
    size_t sidx = (size_t)(b * kDi + d) * kN + n;
    float hs = states[sidx];
    const float4* pD = (const float4*)(dltT + (size_t)d * kMtok + b * kS);
    const float4* pX = (const float4*)(xcT  + (size_t)d * kMtok + b * kS);
    const float4* pZ = (const float4*)(zT   + (size_t)d * kMtok + b * kS);
    const float4* pB = (const float4*)(bcT + (size_t)n * kMtok + b * kS);
    const float4* pC = (const float4*)(bcT + (size_t)(16 + n) * kMtok + b * kS);
    float4 D = pD[0], X = pX[0], Z = pZ[0], Bq = pB[0], Cq = pC[0];
    ushort* yrow = y + (size_t)(b * kS) * kDi + d;
    for (int g = 0; g < kS / 4; ++g) {
        float4 Dn, Xn, Zn, Bn, Cn;
        if (g + 1 < kS / 4) { Dn = pD[g + 1]; Xn = pX[g + 1]; Zn = pZ[g + 1]; Bn = pB[g + 1]; Cn = pC[g + 1]; }
#pragma unroll
        for (int e = 0; e < 4; ++e) {
            float dv = (&D.x)[e], xv = (&X.x)[e], zv = (&Z.x)[e];
            float Bv = (&Bq.x)[e], Cv = (&Cq.x)[e];
            hs = __expf(dv * Areg) * hs + (dv * xv) * Bv;
            float p = hs * Cv;
            p += __shfl_xor(p, 1, 16);
            p += __shfl_xor(p, 2, 16);
            p += __shfl_xor(p, 4, 16);
            p += __shfl_xor(p, 8, 16);
            if (n == 0) yrow[(size_t)(g * 4 + e) * kDi] = f2b((p + xv * dpv) * zv);
        }
        D = Dn; X = Xn; Z = Zn; Bq = Bn; Cq = Cn;
    }
    states[sidx] = hs;
}

// ---------------- refine: initial d = states . C_w -> bf16 ----------------
__global__ void contract_kernel(const float* __restrict__ st, const float* __restrict__ Cw,
                                ushort* __restrict__ dDi)
{
    int i = blockIdx.x * 256 + threadIdx.x;
    int row = i / kDi, di = i - row * kDi;
    int b = row / kNL, s = row - b * kNL;
    const float* sp = st + ((size_t)(s * kB + b) * kDi + di) * kN;
    float acc = 0.f;
#pragma unroll
    for (int nn = 0; nn < kN; ++nn) acc += sp[nn] * Cw[nn];
    dDi[i] = f2b(acc);
}

// ---------------- tiny attention -> bf16 ----------------
__global__ __launch_bounds__(32) void attn_kernel(const float* __restrict__ qkv,
                                                  ushort* __restrict__ o)
{
    int b = blockIdx.x / kNH;
    int hh = blockIdx.x - b * kNH;
    int sq = threadIdx.x;
    if (sq >= kNL) return;
    const float* qrow = qkv + (size_t)(b * kNL + sq) * (3 * kD) + hh * 64;
    float q[64];
#pragma unroll
    for (int e = 0; e < 64; ++e) q[e] = qrow[e];
    float sc[kNL];
    float mx = -1e30f;
    for (int sk = 0; sk < kNL; ++sk) {
        const float* krow = qkv + (size_t)(b * kNL + sk) * (3 * kD) + kD + hh * 64;
        float dt = 0.f;
#pragma unroll
        for (int e = 0; e < 64; ++e) dt += q[e] * krow[e];
        dt *= 0.125f;
        sc[sk] = dt;
        mx = fmaxf(mx, dt);
    }
    float sum = 0.f;
    for (int sk = 0; sk < kNL; ++sk) { sc[sk] = expf(sc[sk] - mx); sum += sc[sk]; }
    float inv = 1.f / sum;
    float out[64];
#pragma unroll
    for (int e = 0; e < 64; ++e) out[e] = 0.f;
    for (int sk = 0; sk < kNL; ++sk) {
        float wgt = sc[sk] * inv;
        const float* vrow = qkv + (size_t)(b * kNL + sk) * (3 * kD) + 2 * kD + hh * 64;
#pragma unroll
        for (int e = 0; e < 64; ++e) out[e] += wgt * vrow[e];
    }
    ushort* orow = o + (size_t)(b * kNL + sq) * kD + hh * 64;
#pragma unroll
    for (int e = 0; e < 64; ++e) orow[e] = f2b(out[e]);
}

} // namespace

extern "C" void kernel_launch(void* const* d_in, const int* in_sizes, int n_in,
                              void* d_out, int out_size, void* d_ws, size_t ws_size,
                              hipStream_t stream)
{
    const int*   q_ids  = (const int*)d_in[0];
    const int*   q_msk  = (const int*)d_in[1];
    const int*   a_ids  = (const int*)d_in[2];
    const int*   a_msk  = (const int*)d_in[3];
    const float* embed  = (const float*)d_in[4];
    const float* norm_w = (const float*)d_in[5];
    const float* ipw    = (const float*)d_in[6];
    const float* cw     = (const float*)d_in[7];
    const float* cb     = (const float*)d_in[8];
    const float* xpw    = (const float*)d_in[9];
    const float* dpw    = (const float*)d_in[10];
    const float* dpb    = (const float*)d_in[11];
    const float* alog   = (const float*)d_in[12];
    const float* dpp    = (const float*)d_in[13];
    const float* opw    = (const float*)d_in[14];
    const float* norm_f = (const float*)d_in[15];
    const float* ln1w   = (const float*)d_in[16];
    const float* ln1b   = (const float*)d_in[17];
    const float* qkvw   = (const float*)d_in[18];
    const float* qkvbi  = (const float*)d_in[19];
    const float* aow    = (const float*)d_in[20];
    const float* aob    = (const float*)d_in[21];
    const float* ln2w   = (const float*)d_in[22];
    const float* ln2b   = (const float*)d_in[23];
    const float* ff1w   = (const float*)d_in[24];
    const float* ff1b   = (const float*)d_in[25];
    const float* ff2w   = (const float*)d_in[26];
    const float* ff2b   = (const float*)d_in[27];
    const float* Cwp    = (const float*)d_in[28];
    const float* powp   = (const float*)d_in[29];
    const float* Bwp    = (const float*)d_in[30];
    const float* piwp   = (const float*)d_in[31];

    // ---- workspace arena ----
    char* base = (char*)d_ws;
    size_t cur = 0;
    auto allocB = [&](size_t bytes) { char* p = base + cur; cur = (cur + bytes + 255) & ~(size_t)255; return p; };
    auto allocF = [&](size_t n) { return (float*)allocB(n * 4); };
    auto allocH = [&](size_t n) { return (ushort*)allocB(n * 2); };

    // fp32
    float* h     = allocF((size_t)kMtok * kD);
    float* xbuf  = allocF((size_t)kMtok * kDi);
    float* zT    = allocF((size_t)kDi * kMtok);
    float* xcT   = allocF((size_t)kDi * kMtok);
    float* bcT   = allocF((size_t)32 * kMtok);
    float* dltT  = allocF((size_t)kDi * kMtok);
    float* st    = allocF((size_t)kNL * kB * kDi * kN);
    float* x768  = allocF((size_t)kMref * kD);
    float* qkvB  = allocF((size_t)kMref * 3 * kD);
    // bf16 activations
    ushort* xin_bf  = allocH((size_t)kMtok * kD);
    ushort* xc_bf   = allocH((size_t)kMtok * kDi);
    ushort* yb_bf   = allocH((size_t)kMtok * kDi);
    ushort* dDi_bf  = allocH((size_t)128 * kDi);
    ushort* tb_bf   = allocH((size_t)128 * kD);
    ushort* o768_bf = allocH((size_t)128 * kD);
    ushort* f3_bf   = allocH((size_t)128 * 4 * kD);
    ushort* x768_bf = allocH((size_t)128 * kD);
    // bf16 weights
    ushort* xpw2    = allocH((size_t)kNL * kNxPad * kDi);  // [32 bc rows | 1536 Wc rows]
    ushort* dpw_bf  = allocH((size_t)kNL * kDi * 64);
    ushort* xpwdtT  = allocH((size_t)kNL * kDi * 64);
    ushort* powp_bf = allocH((size_t)kD * kDi);
    ushort* qkvw_bf = allocH((size_t)3 * kD * kD);
    ushort* aow_bf  = allocH((size_t)kD * kD);
    ushort* ff1w_bf = allocH((size_t)4 * kD * kD);
    ushort* ff2w_bf = allocH((size_t)kD * 4 * kD);
    ushort* piw_bf  = allocH((size_t)kDi * kD);
    ushort* emb_bf  = allocH((size_t)kVp * kD);

    size_t base_end = cur;
    ushort* ipw_all = allocH((size_t)kNL * 2 * kDi * kD);
    ushort* opw_all = allocH((size_t)kNL * kD * kDi);
    bool full = (cur <= ws_size);
    ushort* ipw_stg = nullptr;
    ushort* opw_stg = nullptr;
    if (!full) {
        cur = base_end;
        ipw_stg = allocH((size_t)2 * kDi * kD);
        opw_stg = allocH((size_t)kD * kDi);
        if (cur > ws_size) return;
    }

    auto cvt = [&](const float* s, ushort* d, size_t n) {
        cvt_kernel<<<dim3((unsigned)((n / 4 + 255) / 256)), dim3(256), 0, stream>>>(s, d, (int)n);
    };

    hipMemsetAsync(st, 0, sizeof(float) * (size_t)kNL * kB * kDi * kN, stream);
    // zero xpw2 (pad rows must be finite; written rows overwritten below)
    hipMemsetAsync(xpw2, 0, sizeof(ushort) * (size_t)kNL * kNxPad * kDi, stream);

    // ---- setup: weight conversions + Wc = dpw @ xpw_dt per layer ----
    cvt_dpw_kernel<<<dim3(9216), dim3(256), 0, stream>>>(dpw, dpw_bf);
    cvt_xpwdtT_kernel<<<dim3(9216), dim3(256), 0, stream>>>(xpw, xpwdtT);
    cvt_bc_kernel<<<dim3(4608), dim3(256), 0, stream>>>(xpw, xpw2);
    for (int l = 0; l < kNL; ++l) {
        gemm<64, 64, 0, 0, 0, 2, 3>(dpw_bf + (size_t)l * kDi * 64, 64,
                                    xpwdtT + (size_t)l * kDi * 64, 64,
                                    nullptr, 0,
                                    xpw2 + (size_t)l * kNxPad * kDi + 32 * kDi, kDi,
                                    nullptr, nullptr, nullptr, kDi, kDi, 64, stream);
    }
    cvt(powp, powp_bf, (size_t)kD * kDi);
    cvt(qkvw, qkvw_bf, (size_t)3 * kD * kD);
    cvt(aow,  aow_bf,  (size_t)kD * kD);
    cvt(ff1w, ff1w_bf, (size_t)4 * kD * kD);
    cvt(ff2w, ff2w_bf, (size_t)kD * 4 * kD);
    cvt(piwp, piw_bf,  (size_t)kDi * kD);
    cvt(embed, emb_bf, (size_t)kV * kD);
    if (full) {
        cvt(ipw, ipw_all, (size_t)kNL * 2 * kDi * kD);
        cvt(opw, opw_all, (size_t)kNL * kD * kDi);
    }

    for (int pass = 0; pass < 2; ++pass) {
        const int* ids = pass ? a_ids : q_ids;
        const int* msk = pass ? a_msk : q_msk;

        embed_kernel<<<dim3(kMtok * kD / 256), dim3(256), 0, stream>>>(ids, msk, embed, h);

        for (int l = 0; l < kNL; ++l) {
            const ushort* ipw_l;
            const ushort* opw_l;
            if (full) {
                ipw_l = ipw_all + (size_t)l * 2 * kDi * kD;
                opw_l = opw_all + (size_t)l * kD * kDi;
            } else {
                cvt(ipw + (size_t)l * 2 * kDi * kD, ipw_stg, (size_t)2 * kDi * kD);
                cvt(opw + (size_t)l * kD * kDi, opw_stg, (size_t)kD * kDi);
                ipw_l = ipw_stg;
                opw_l = opw_stg;
            }
            rms_kernel<<<dim3(kMtok), dim3(256), 0, stream>>>(h, norm_w + (size_t)l * kD, xin_bf);
            gemm<64, 64, 0, 0, 0, 5, 3>(xin_bf, kD, ipw_l, kD, xbuf, kDi, nullptr, 0, zT,
                                        nullptr, nullptr, kMtok, 2 * kDi, kD, stream);
            conv_kernel<<<dim3(kDi / 256, kMtok / 16), dim3(256), 0, stream>>>(
                xbuf, cw + (size_t)l * kDi * kK, cb + (size_t)l * kDi, xc_bf, xcT);
            gemm<64, 64, 0, 0, 0, 6, 3>(xc_bf, kDi, xpw2 + (size_t)l * kNxPad * kDi, kDi,
                                        dltT, 0, nullptr, 0, bcT,
                                        dpb + (size_t)l * kDi, nullptr, kMtok, kNx, kDi, stream);
            scan_kernel<<<dim3(kB * kDi * kN / 256), dim3(256), 0, stream>>>(
                dltT, xcT, zT, bcT, alog + (size_t)l * kDi * kN, dpp + (size_t)l * kDi,
                st + (size_t)l * kB * kDi * kN, yb_bf);
            gemm<64, 64, 0, 0, 1, 0, 3>(yb_bf, kDi, opw_l, kDi, h, kD, nullptr, 0, nullptr,
                                        nullptr, nullptr, kMtok, kD, kDi, stream);
        }

        if (pass == 0) {
            contract_kernel<<<dim3(kMref * kDi / 256), dim3(256), 0, stream>>>(st, Cwp, dDi_bf);
            for (int it = 0; it < 12; ++it) {
                gemm<64, 64, 0, 0, 0, 0, 3>(dDi_bf, kDi, powp_bf, kDi, x768, kD, nullptr, 0, nullptr,
                                            nullptr, nullptr, kMref, kD, kDi, stream);
                ln_kernel<<<dim3(kMref), dim3(256), 0, stream>>>(x768, ln1w, ln1b, tb_bf);
                gemm<64, 64, 1, 0, 0, 0, 3>(tb_bf, kD, qkvw_bf, kD, qkvB, 3 * kD, nullptr, 0, nullptr,
                                            qkvbi, nullptr, kMref, 3 * kD, kD, stream);
                attn_kernel<<<dim3(kB * kNH), dim3(32), 0, stream>>>(qkvB, o768_bf);
                gemm<64, 64, 1, 0, 1, 0, 3>(o768_bf, kD, aow_bf, kD, x768, kD, nullptr, 0, nullptr,
                                            aob, nullptr, kMref, kD, kD, stream);
                ln_kernel<<<dim3(kMref), dim3(256), 0, stream>>>(x768, ln2w, ln2b, tb_bf);
                gemm<64, 64, 1, 2, 0, 2, 3>(tb_bf, kD, ff1w_bf, kD, nullptr, 0, f3_bf, 4 * kD, nullptr,
                                            ff1b, nullptr, kMref, 4 * kD, kD, stream);
                gemm<64, 64, 1, 0, 1, 1, 3>(f3_bf, 4 * kD, ff2w_bf, 4 * kD, x768, kD, x768_bf, kD, nullptr,
                                            ff2b, nullptr, kMref, kD, 4 * kD, stream);
                gemm<64, 64, 0, 0, 0, 7, 3>(x768_bf, kD, piw_bf, kD, nullptr, 0, dDi_bf, kDi, st,
                                            Bwp, Cwp, kMref, kDi, kD, stream);
            }
        } else {
            rms_kernel<<<dim3(kMtok), dim3(256), 0, stream>>>(h, norm_f, xin_bf);
            gemm<128, 128, 0, 0, 0, 0, 2>(xin_bf, kD, emb_bf, kD, (float*)d_out, kV, nullptr, 0, nullptr,
                                          nullptr, nullptr, kMtok, kV, kD, stream);
        }
    }
}

// Round 7
// 8636.510 us; speedup vs baseline: 1.6435x; 1.0716x over previous
//
#include <hip/hip_runtime.h>
#include <math.h>

namespace {

constexpr int kNL = 24, kD = 768, kDi = 1536, kN = 16, kR = 48, kK = 4, kV = 50280, kNH = 12;
constexpr int kB = 4, kS = 256;
constexpr int kMtok = kB * kS;   // 1024 token rows
constexpr int kMref = kB * kNL;  // 96 refine rows
constexpr int kVp = 50304;       // kV padded to 128

using bf16x8   = __attribute__((ext_vector_type(8))) short;
using f32x4    = __attribute__((ext_vector_type(4))) float;
using ushort8v = __attribute__((ext_vector_type(8))) unsigned short;

__device__ __forceinline__ float siluf(float x) { return x / (1.f + __expf(-x)); }

__device__ __forceinline__ ushort f2b(float f) {
    union { float f; unsigned u; } v; v.f = f;
    unsigned u = v.u;
    unsigned r = (u + 0x7FFFu + ((u >> 16) & 1u)) >> 16;
    return (ushort)r;
}
__device__ __forceinline__ float b2f(ushort u) {
    union { unsigned u; float f; } v; v.u = (unsigned)u << 16; return v.f;
}

#define GLOAD_LDS(g, l) \
    __builtin_amdgcn_global_load_lds((const __attribute__((address_space(1))) void*)(g), \
                                     (__attribute__((address_space(3))) void*)(l), 16, 0, 0)

// ---------------- bf16 MFMA GEMM: C[M,N] = A[M,K] @ B[N,K]^T ----------------
// PIPE=3: 3-buffer LDS, counted vmcnt + raw s_barrier.
// PIPE=2: classic 2-buffer __syncthreads (logits).
// ACT: 0 none, 1 softplus, 2 gelu(exact).
// OUTMODE:
//  0 fp32 C (+RES)     1 fp32 C + bf16 Cbf     2 bf16 Cbf only
//  3 x_proj: gn<48 -> dt-in bf16 (Cbf, ld 64; cols 48..63 zeroed);
//            gn in [48,80) -> C2[(gn-48)*1024+gm] fp32 (bc^T)
//  4 dt:     ((ushort*)C2)[gn*1024+gm] = bf16(v)   (dlt^T, ACT applied)
//  7 pi + state update: st (C2) += v*bias[nn]; dDi (Cbf) = dot(st, aux)
// SSQ=1 (OUTMODE0, 64x64 only): C2 = ssq_part[gridX][1024], deterministic
//       per-block row sum of v^2 (shuffle over ccol + 2-wave LDS combine).
template <int BM, int BN, int BIAS, int ACT, int RES, int OUTMODE, int PIPE, int SSQ = 0>
__global__ __launch_bounds__(256, (PIPE == 3 ? 3 : 2)) void gemm_bf16(
    const ushort* __restrict__ A, int lda,
    const ushort* __restrict__ B, int ldb,
    float* __restrict__ C, int ldc,
    ushort* __restrict__ Cbf, int ldcb,
    float* __restrict__ C2,
    const float* __restrict__ bias,
    const float* __restrict__ aux,
    int M, int N, int K)
{
    constexpr int ACH = BM / 32;
    constexpr int BCH = BN / 32;
    constexpr int MI  = BM / 32;
    constexpr int NJ  = BN / 32;

    __shared__ ushort As[PIPE][BM * 64];
    __shared__ ushort Bs[PIPE][BN * 64];

    const int tid  = threadIdx.x;
    const int lane = tid & 63;
    const int wave = tid >> 6;
    const int m0 = blockIdx.y * BM;
    const int n0 = blockIdx.x * BN;
    const int wr = (wave >> 1) * (BM / 2);
    const int wc = (wave & 1) * (BN / 2);

    f32x4 acc[MI][NJ];
#pragma unroll
    for (int i = 0; i < MI; ++i)
#pragma unroll
        for (int j = 0; j < NJ; ++j) acc[i][j] = f32x4{0.f, 0.f, 0.f, 0.f};

    const int srow = lane >> 3;
    const int scol = ((lane & 7) ^ srow) * 8;
    const ushort* gA[ACH];
    const ushort* gB[BCH];
#pragma unroll
    for (int g = 0; g < ACH; ++g)
        gA[g] = A + (size_t)(m0 + (g * 4 + wave) * 8 + srow) * lda + scol;
#pragma unroll
    for (int g = 0; g < BCH; ++g)
        gB[g] = B + (size_t)(n0 + (g * 4 + wave) * 8 + srow) * ldb + scol;

    const int frow = lane & 15;
    const int kh   = lane >> 4;
    const int nt   = K >> 6;

    auto stage = [&](int t, int buf) {
        const int off = t * 64;
#pragma unroll
        for (int g = 0; g < ACH; ++g) GLOAD_LDS(gA[g] + off, &As[buf][(g * 4 + wave) * 512]);
#pragma unroll
        for (int g = 0; g < BCH; ++g) GLOAD_LDS(gB[g] + off, &Bs[buf][(g * 4 + wave) * 512]);
    };
    auto compute = [&](int buf) {
#pragma unroll
        for (int s = 0; s < 2; ++s) {
            bf16x8 fa[MI], fb[NJ];
#pragma unroll
            for (int i = 0; i < MI; ++i) {
                int r = wr + i * 16 + frow;
                int slot = (s * 4 + kh) ^ (r & 7);
                fa[i] = *(const bf16x8*)&As[buf][r * 64 + slot * 8];
            }
#pragma unroll
            for (int j = 0; j < NJ; ++j) {
                int r = wc + j * 16 + frow;
                int slot = (s * 4 + kh) ^ (r & 7);
                fb[j] = *(const bf16x8*)&Bs[buf][r * 64 + slot * 8];
            }
#pragma unroll
            for (int i = 0; i < MI; ++i)
#pragma unroll
                for (int j = 0; j < NJ; ++j)
                    acc[i][j] = __builtin_amdgcn_mfma_f32_16x16x32_bf16(fa[i], fb[j], acc[i][j], 0, 0, 0);
        }
    };

    if constexpr (PIPE == 3) {
        stage(0, 0);
        if (nt > 1) stage(1, 1);
        for (int t = 0; t < nt; ++t) {
            if (t < nt - 1) {
                asm volatile("s_waitcnt vmcnt(%0)" :: "n"(ACH + BCH) : "memory");
            } else {
                asm volatile("s_waitcnt vmcnt(0)" ::: "memory");
            }
            __builtin_amdgcn_s_barrier();
            if (t + 2 < nt) stage(t + 2, (t + 2) % 3);
            compute(t % 3);
        }
        __builtin_amdgcn_s_barrier();
    } else {
        stage(0, 0);
        __syncthreads();
        int cur = 0;
        for (int t = 0; t < nt; ++t) {
            if (t + 1 < nt) stage(t + 1, cur ^ 1);
            compute(cur);
            __syncthreads();
            cur ^= 1;
        }
    }

    // epilogue: C/D layout col = lane&15, row = (lane>>4)*4 + q
    const int ccol = lane & 15;
    const int crow = (lane >> 4) * 4;
    float rsq[MI][4];
    if constexpr (SSQ) {
#pragma unroll
        for (int i = 0; i < MI; ++i)
#pragma unroll
            for (int q = 0; q < 4; ++q) rsq[i][q] = 0.f;
    }
#pragma unroll
    for (int i = 0; i < MI; ++i) {
#pragma unroll
        for (int j = 0; j < NJ; ++j) {
            int gn = n0 + wc + j * 16 + ccol;
            if (gn >= N) continue;
            float bv = BIAS ? bias[gn] : 0.f;
#pragma unroll
            for (int q = 0; q < 4; ++q) {
                int gm = m0 + wr + i * 16 + crow + q;
                if (gm >= M) continue;
                float v = acc[i][j][q] + bv;
                if (ACT == 1) v = fmaxf(v, 0.f) + log1pf(expf(-fabsf(v)));
                if (ACT == 2) v = 0.5f * v * (1.f + erff(v * 0.70710678118654752f));
                if (OUTMODE == 3) {
                    if (gn < 48) Cbf[(size_t)gm * 64 + gn] = f2b(v);
                    else if (gn < 64) { Cbf[(size_t)gm * 64 + gn] = 0; C2[(size_t)(gn - 48) * kMtok + gm] = v; }
                    else if (gn < 80) C2[(size_t)(gn - 48) * kMtok + gm] = v;
                } else if (OUTMODE == 4) {
                    ((ushort*)C2)[(size_t)gn * kMtok + gm] = f2b(v);
                } else if (OUTMODE == 7) {
                    int bb = gm / kNL, ss = gm - bb * kNL;
                    float* stp = C2 + ((size_t)(ss * kB + bb) * kDi + gn) * kN;
                    float a2 = 0.f;
#pragma unroll
                    for (int nn = 0; nn < kN; ++nn) {
                        float sv = stp[nn] + v * bias[nn];
                        stp[nn] = sv;
                        a2 += sv * aux[nn];
                    }
                    Cbf[(size_t)gm * ldcb + gn] = f2b(a2);
                } else {
                    size_t ci = (size_t)gm * ldc + gn;
                    if (RES) v += C[ci];
                    if (OUTMODE != 2) C[ci] = v;
                    if (OUTMODE == 1 || OUTMODE == 2) Cbf[(size_t)gm * ldcb + gn] = f2b(v);
                    if constexpr (SSQ) rsq[i][q] += v * v;
                }
            }
        }
    }
    if constexpr (SSQ) {
        // deterministic row-sum of v^2: shuffle over 16 ccol lanes, then combine 2 waves
#pragma unroll
        for (int i = 0; i < MI; ++i)
#pragma unroll
            for (int q = 0; q < 4; ++q) {
                rsq[i][q] += __shfl_xor(rsq[i][q], 1, 16);
                rsq[i][q] += __shfl_xor(rsq[i][q], 2, 16);
                rsq[i][q] += __shfl_xor(rsq[i][q], 4, 16);
                rsq[i][q] += __shfl_xor(rsq[i][q], 8, 16);
            }
        float* red = (float*)&As[0][0];   // 128 floats scratch
        __syncthreads();
        if ((lane & 15) == 0) {
#pragma unroll
            for (int i = 0; i < MI; ++i)
#pragma unroll
                for (int q = 0; q < 4; ++q) {
                    int rl = (wave >> 1) * 32 + i * 16 + (lane >> 4) * 4 + q;
                    red[(wave & 1) * 64 + rl] = rsq[i][q];
                }
        }
        __syncthreads();
        if (tid < 64) C2[(size_t)blockIdx.x * kMtok + m0 + tid] = red[tid] + red[64 + tid];
    }
}

template <int BM, int BN, int BIAS, int ACT, int RES, int OUTMODE, int PIPE, int SSQ = 0>
static void gemm(const ushort* A, int lda, const ushort* B, int ldb,
                 float* C, int ldc, ushort* Cb, int ldcb, float* C2,
                 const float* bias, const float* aux, int M, int N, int K, hipStream_t s)
{
    dim3 g((N + BN - 1) / BN, (M + BM - 1) / BM);
    gemm_bf16<BM, BN, BIAS, ACT, RES, OUTMODE, PIPE, SSQ><<<g, dim3(256), 0, s>>>(
        A, lda, B, ldb, C, ldc, Cb, ldcb, C2, bias, aux, M, N, K);
}

// ------- in_proj with fused RMSNorm: reads h fp32 + ssq_part, reg-staged A ---
// Writes x half bf16 row-major (Xbf) and silu(z)^T bf16 (zTb).
__global__ __launch_bounds__(256, 4) void gemm_rms(
    const float* __restrict__ hbuf, const float* __restrict__ ssq, // [12][1024]
    const float* __restrict__ nw,
    const ushort* __restrict__ B, int ldb,
    ushort* __restrict__ Xbf, ushort* __restrict__ zTb,
    int M, int N, int K)
{
    constexpr int MI = 2, NJ = 2, BCH = 2;
    __shared__ ushort As[2][64 * 64];
    __shared__ ushort Bs[2][64 * 64];
    const int tid  = threadIdx.x;
    const int lane = tid & 63;
    const int wave = tid >> 6;
    const int m0 = blockIdx.y * 64;
    const int n0 = blockIdx.x * 64;
    const int wr = (wave >> 1) * 32;
    const int wc = (wave & 1) * 32;

    f32x4 acc[MI][NJ];
#pragma unroll
    for (int i = 0; i < MI; ++i)
#pragma unroll
        for (int j = 0; j < NJ; ++j) acc[i][j] = f32x4{0.f, 0.f, 0.f, 0.f};

    const int srow = lane >> 3;
    const int scol = ((lane & 7) ^ srow) * 8;
    const ushort* gB[BCH];
#pragma unroll
    for (int g = 0; g < BCH; ++g)
        gB[g] = B + (size_t)(n0 + (g * 4 + wave) * 8 + srow) * ldb + scol;

    int arow[2];
    float rs[2];
#pragma unroll
    for (int g = 0; g < 2; ++g) {
        arow[g] = m0 + (g * 4 + wave) * 8 + srow;
        float s = 0.f;
#pragma unroll
        for (int c = 0; c < 12; ++c) s += ssq[c * kMtok + arow[g]];
        rs[g] = rsqrtf(s * (1.f / 768.f) + 1e-5f);
    }

    const int frow = lane & 15;
    const int kh   = lane >> 4;
    const int nt   = K >> 6;

    float4 av[2][2], wv[2];
    auto loadA = [&](int t) {
        int k = t * 64 + scol;
        wv[0] = *(const float4*)&nw[k];
        wv[1] = *(const float4*)&nw[k + 4];
#pragma unroll
        for (int g = 0; g < 2; ++g) {
            av[g][0] = *(const float4*)&hbuf[(size_t)arow[g] * K + k];
            av[g][1] = *(const float4*)&hbuf[(size_t)arow[g] * K + k + 4];
        }
    };
    auto writeA = [&](int buf) {
#pragma unroll
        for (int g = 0; g < 2; ++g) {
            ushort8v o;
            o[0] = f2b(av[g][0].x * rs[g] * wv[0].x);
            o[1] = f2b(av[g][0].y * rs[g] * wv[0].y);
            o[2] = f2b(av[g][0].z * rs[g] * wv[0].z);
            o[3] = f2b(av[g][0].w * rs[g] * wv[0].w);
            o[4] = f2b(av[g][1].x * rs[g] * wv[1].x);
            o[5] = f2b(av[g][1].y * rs[g] * wv[1].y);
            o[6] = f2b(av[g][1].z * rs[g] * wv[1].z);
            o[7] = f2b(av[g][1].w * rs[g] * wv[1].w);
            *(ushort8v*)&As[buf][(g * 4 + wave) * 512 + lane * 8] = o;
        }
    };
    auto stageB = [&](int t, int buf) {
#pragma unroll
        for (int g = 0; g < BCH; ++g) GLOAD_LDS(gB[g] + t * 64, &Bs[buf][(g * 4 + wave) * 512]);
    };
    auto compute = [&](int buf) {
#pragma unroll
        for (int s = 0; s < 2; ++s) {
            bf16x8 fa[MI], fb[NJ];
#pragma unroll
            for (int i = 0; i < MI; ++i) {
                int r = wr + i * 16 + frow;
                int slot = (s * 4 + kh) ^ (r & 7);
                fa[i] = *(const bf16x8*)&As[buf][r * 64 + slot * 8];
            }
#pragma unroll
            for (int j = 0; j < NJ; ++j) {
                int r = wc + j * 16 + frow;
                int slot = (s * 4 + kh) ^ (r & 7);
                fb[j] = *(const bf16x8*)&Bs[buf][r * 64 + slot * 8];
            }
#pragma unroll
            for (int i = 0; i < MI; ++i)
#pragma unroll
                for (int j = 0; j < NJ; ++j)
                    acc[i][j] = __builtin_amdgcn_mfma_f32_16x16x32_bf16(fa[i], fb[j], acc[i][j], 0, 0, 0);
        }
    };

    loadA(0);
    stageB(0, 0);
    writeA(0);
    __syncthreads();
    int cur = 0;
    for (int t = 0; t < nt; ++t) {
        if (t + 1 < nt) { loadA(t + 1); stageB(t + 1, cur ^ 1); }
        compute(cur);
        if (t + 1 < nt) writeA(cur ^ 1);
        __syncthreads();
        cur ^= 1;
    }

    const int ccol = lane & 15;
    const int crow = (lane >> 4) * 4;
#pragma unroll
    for (int i = 0; i < MI; ++i) {
#pragma unroll
        for (int j = 0; j < NJ; ++j) {
            int gn = n0 + wc + j * 16 + ccol;
#pragma unroll
            for (int q = 0; q < 4; ++q) {
                int gm = m0 + wr + i * 16 + crow + q;
                float v = acc[i][j][q];
                if (gn < kDi) Xbf[(size_t)gm * kDi + gn] = f2b(v);
                else zTb[(size_t)(gn - kDi) * kMtok + gm] = f2b(siluf(v));
            }
        }
    }
}

// ---------------- conversions ----------------
__global__ void cvt_kernel(const float* __restrict__ src, ushort* __restrict__ dst, int n) {
    int i = (blockIdx.x * 256 + threadIdx.x) * 4;
    if (i >= n) return;
    float4 v = *(const float4*)(src + i);
    ushort4 o; o.x = f2b(v.x); o.y = f2b(v.y); o.z = f2b(v.z); o.w = f2b(v.w);
    *(ushort4*)(dst + i) = o;
}

// xpw [24][80][1536] -> padded [24][128][1536]
__global__ void cvt_xpw_kernel(const float* __restrict__ src, ushort* __restrict__ dst) {
    int i = (blockIdx.x * 256 + threadIdx.x) * 4;
    if (i >= 24 * 80 * 1536) return;
    int l = i / (80 * 1536), r = i - l * (80 * 1536);
    int row = r / 1536, col = r - row * 1536;
    float4 v = *(const float4*)(src + i);
    ushort4 o; o.x = f2b(v.x); o.y = f2b(v.y); o.z = f2b(v.z); o.w = f2b(v.w);
    *(ushort4*)(dst + ((size_t)(l * 128 + row)) * 1536 + col) = o;
}

// dpw [24][1536][48] -> padded [24][1536][64] (K-pad zero)
__global__ void cvt_dpw_kernel(const float* __restrict__ src, ushort* __restrict__ dst) {
    int i = blockIdx.x * 256 + threadIdx.x;
    if (i >= 24 * 1536 * 64) return;
    int col = i & 63, row = i >> 6;
    dst[i] = (col < 48) ? f2b(src[(size_t)row * 48 + col]) : (ushort)0;
}

// ---------------- embedding (+ ssq_part init) ----------------
__global__ void embed_kernel(const int* __restrict__ ids, const int* __restrict__ msk,
                             const float* __restrict__ embed, float* __restrict__ h,
                             float* __restrict__ ssq)
{
    int i = blockIdx.x * 256 + threadIdx.x;
    int row = i / kD, col = i - row * kD;
    float v = embed[(size_t)ids[row] * kD + col] * (float)msk[row];
    h[i] = v;
    float s = v * v;
    s += __shfl_xor(s, 1);  s += __shfl_xor(s, 2);  s += __shfl_xor(s, 4);
    s += __shfl_xor(s, 8);  s += __shfl_xor(s, 16); s += __shfl_xor(s, 32);
    if ((threadIdx.x & 63) == 0) ssq[(col >> 6) * kMtok + row] = s;
}

// ---------------- RMSNorm -> bf16 (final norm before logits only) ---------
__global__ __launch_bounds__(256) void rms_kernel(const float* __restrict__ x,
                                                  const float* __restrict__ w,
                                                  ushort* __restrict__ out)
{
    __shared__ float red[256];
    int row = blockIdx.x, tid = threadIdx.x;
    const float* xr = x + (size_t)row * kD;
    float s = 0.f;
    for (int j = tid; j < kD; j += 256) { float v = xr[j]; s += v * v; }
    red[tid] = s; __syncthreads();
    for (int o = 128; o > 0; o >>= 1) { if (tid < o) red[tid] += red[tid + o]; __syncthreads(); }
    float rs = rsqrtf(red[0] / (float)kD + 1e-5f);
    for (int j = tid; j < kD; j += 256) out[(size_t)row * kD + j] = f2b(xr[j] * rs * w[j]);
}

// ---------------- LayerNorm -> bf16 ----------------
__global__ __launch_bounds__(256) void ln_kernel(const float* __restrict__ x,
                                                 const float* __restrict__ w,
                                                 const float* __restrict__ b,
                                                 ushort* __restrict__ out)
{
    __shared__ float r1[256], r2[256];
    int row = blockIdx.x, tid = threadIdx.x;
    const float* xr = x + (size_t)row * kD;
    float s = 0.f, s2 = 0.f;
    for (int j = tid; j < kD; j += 256) { float v = xr[j]; s += v; s2 += v * v; }
    r1[tid] = s; r2[tid] = s2; __syncthreads();
    for (int o = 128; o > 0; o >>= 1) {
        if (tid < o) { r1[tid] += r1[tid + o]; r2[tid] += r2[tid + o]; }
        __syncthreads();
    }
    float mean = r1[0] / (float)kD;
    float var = r2[0] / (float)kD - mean * mean;
    float rsv = rsqrtf(var + 1e-5f);
    for (int j = tid; j < kD; j += 256)
        out[(size_t)row * kD + j] = f2b((xr[j] - mean) * rsv * w[j] + b[j]);
}

// ---------------- causal conv (K=4) + bias + silu (bf16 in/out) ------------
__global__ __launch_bounds__(256) void conv_kernel(
    const ushort* __restrict__ xb, const float* __restrict__ cw,
    const float* __restrict__ cb, ushort* __restrict__ xc_bf,
    ushort* __restrict__ xcT)
{
    int d   = blockIdx.x * 256 + threadIdx.x;
    int bt0 = blockIdx.y * 16;
    int t0  = bt0 & (kS - 1);
    float w0 = cw[d * 4], w1 = cw[d * 4 + 1], w2 = cw[d * 4 + 2], w3 = cw[d * 4 + 3];
    float bias = cb[d];
    float xv[19];
#pragma unroll
    for (int j = 0; j < 19; ++j) {
        int tt = t0 - 3 + j;
        xv[j] = (tt >= 0) ? b2f(xb[(size_t)(bt0 - 3 + j) * kDi + d]) : 0.f;
    }
    ushort8v o0, o1;
#pragma unroll
    for (int e = 0; e < 16; ++e) {
        float s = bias + xv[e] * w0 + xv[e + 1] * w1 + xv[e + 2] * w2 + xv[e + 3] * w3;
        ushort us = f2b(siluf(s));
        xc_bf[(size_t)(bt0 + e) * kDi + d] = us;
        if (e < 8) o0[e] = us; else o1[e - 8] = us;
    }
    *(ushort8v*)(xcT + (size_t)d * kMtok + bt0)     = o0;
    *(ushort8v*)(xcT + (size_t)d * kMtok + bt0 + 8) = o1;
}

// ---------------- selective scan + gating (bf16 t-contiguous inputs) -------
__global__ __launch_bounds__(256) void scan_kernel(
    const ushort* __restrict__ dltT, const ushort* __restrict__ xcT,
    const ushort* __restrict__ zT, const float* __restrict__ bcT,
    const float* __restrict__ alog, const float* __restrict__ dp,
    float* __restrict__ states, ushort* __restrict__ y)
{
    int gid = blockIdx.x * 256 + threadIdx.x;
    int n = gid & 15;
    int d = (gid >> 4) % kDi;
    int b = gid / (kDi * kN);
    float Areg = -__expf(alog[d * kN + n]);
    float dpv = dp[d];
    size_t sidx = (size_t)(b * kDi + d) * kN + n;
    float hs = states[sidx];
    const ushort8v* pD = (const ushort8v*)(dltT + (size_t)d * kMtok + b * kS);
    const ushort8v* pX = (const ushort8v*)(xcT  + (size_t)d * kMtok + b * kS);
    const ushort8v* pZ = (const ushort8v*)(zT   + (size_t)d * kMtok + b * kS);
    const float4* pB = (const float4*)(bcT + (size_t)n * kMtok + b * kS);
    const float4* pC = (const float4*)(bcT + (size_t)(16 + n) * kMtok + b * kS);
    ushort8v D = pD[0], X = pX[0], Z = pZ[0];
    float4 B0 = pB[0], B1 = pB[1], C0 = pC[0], C1 = pC[1];
    ushort* yrow = y + (size_t)(b * kS) * kDi + d;
    for (int g = 0; g < kS / 8; ++g) {
        ushort8v Dn, Xn, Zn; float4 Bn0, Bn1, Cn0, Cn1;
        if (g + 1 < kS / 8) {
            Dn = pD[g + 1]; Xn = pX[g + 1]; Zn = pZ[g + 1];
            Bn0 = pB[2 * g + 2]; Bn1 = pB[2 * g + 3];
            Cn0 = pC[2 * g + 2]; Cn1 = pC[2 * g + 3];
        }
#pragma unroll
        for (int e = 0; e < 8; ++e) {
            float dv = b2f(D[e]), xv = b2f(X[e]), zv = b2f(Z[e]);
            float Bv = (e < 4) ? (&B0.x)[e] : (&B1.x)[e - 4];
            float Cv = (e < 4) ? (&C0.x)[e] : (&C1.x)[e - 4];
            hs = __expf(dv * Areg) * hs + (dv * xv) * Bv;
            float p = hs * Cv;
            p += __shfl_xor(p, 1, 16);
            p += __shfl_xor(p, 2, 16);
            p += __shfl_xor(p, 4, 16);
            p += __shfl_xor(p, 8, 16);
            if (n == 0) yrow[(size_t)(g * 8 + e) * kDi] = f2b((p + xv * dpv) * zv);
        }
        D = Dn; X = Xn; Z = Zn; B0 = Bn0; B1 = Bn1; C0 = Cn0; C1 = Cn1;
    }
    states[sidx] = hs;
}

// ---------------- refine: initial d = states . C_w -> bf16 ----------------
__global__ void contract_kernel(const float* __restrict__ st, const float* __restrict__ Cw,
                                ushort* __restrict__ dDi)
{
    int i = blockIdx.x * 256 + threadIdx.x;
    int row = i / kDi, di = i - row * kDi;
    int b = row / kNL, s = row - b * kNL;
    const float* sp = st + ((size_t)(s * kB + b) * kDi + di) * kN;
    float acc = 0.f;
#pragma unroll
    for (int nn = 0; nn < kN; ++nn) acc += sp[nn] * Cw[nn];
    dDi[i] = f2b(acc);
}

// ---------------- tiny attention -> bf16 ----------------
__global__ __launch_bounds__(32) void attn_kernel(const float* __restrict__ qkv,
                                                  ushort* __restrict__ o)
{
    int b = blockIdx.x / kNH;
    int hh = blockIdx.x - b * kNH;
    int sq = threadIdx.x;
    if (sq >= kNL) return;
    const float* qrow = qkv + (size_t)(b * kNL + sq) * (3 * kD) + hh * 64;
    float q[64];
#pragma unroll
    for (int e = 0; e < 64; ++e) q[e] = qrow[e];
    float sc[kNL];
    float mx = -1e30f;
    for (int sk = 0; sk < kNL; ++sk) {
        const float* krow = qkv + (size_t)(b * kNL + sk) * (3 * kD) + kD + hh * 64;
        float dt = 0.f;
#pragma unroll
        for (int e = 0; e < 64; ++e) dt += q[e] * krow[e];
        dt *= 0.125f;
        sc[sk] = dt;
        mx = fmaxf(mx, dt);
    }
    float sum = 0.f;
    for (int sk = 0; sk < kNL; ++sk) { sc[sk] = expf(sc[sk] - mx); sum += sc[sk]; }
    float inv = 1.f / sum;
    float out[64];
#pragma unroll
    for (int e = 0; e < 64; ++e) out[e] = 0.f;
    for (int sk = 0; sk < kNL; ++sk) {
        float wgt = sc[sk] * inv;
        const float* vrow = qkv + (size_t)(b * kNL + sk) * (3 * kD) + 2 * kD + hh * 64;
#pragma unroll
        for (int e = 0; e < 64; ++e) out[e] += wgt * vrow[e];
    }
    ushort* orow = o + (size_t)(b * kNL + sq) * kD + hh * 64;
#pragma unroll
    for (int e = 0; e < 64; ++e) orow[e] = f2b(out[e]);
}

} // namespace

extern "C" void kernel_launch(void* const* d_in, const int* in_sizes, int n_in,
                              void* d_out, int out_size, void* d_ws, size_t ws_size,
                              hipStream_t stream)
{
    const int*   q_ids  = (const int*)d_in[0];
    const int*   q_msk  = (const int*)d_in[1];
    const int*   a_ids  = (const int*)d_in[2];
    const int*   a_msk  = (const int*)d_in[3];
    const float* embed  = (const float*)d_in[4];
    const float* norm_w = (const float*)d_in[5];
    const float* ipw    = (const float*)d_in[6];
    const float* cw     = (const float*)d_in[7];
    const float* cb     = (const float*)d_in[8];
    const float* xpw    = (const float*)d_in[9];
    const float* dpw    = (const float*)d_in[10];
    const float* dpb    = (const float*)d_in[11];
    const float* alog   = (const float*)d_in[12];
    const float* dpp    = (const float*)d_in[13];
    const float* opw    = (const float*)d_in[14];
    const float* norm_f = (const float*)d_in[15];
    const float* ln1w   = (const float*)d_in[16];
    const float* ln1b   = (const float*)d_in[17];
    const float* qkvw   = (const float*)d_in[18];
    const float* qkvbi  = (const float*)d_in[19];
    const float* aow    = (const float*)d_in[20];
    const float* aob    = (const float*)d_in[21];
    const float* ln2w   = (const float*)d_in[22];
    const float* ln2b   = (const float*)d_in[23];
    const float* ff1w   = (const float*)d_in[24];
    const float* ff1b   = (const float*)d_in[25];
    const float* ff2w   = (const float*)d_in[26];
    const float* ff2b   = (const float*)d_in[27];
    const float* Cwp    = (const float*)d_in[28];
    const float* powp   = (const float*)d_in[29];
    const float* Bwp    = (const float*)d_in[30];
    const float* piwp   = (const float*)d_in[31];

    // ---- workspace arena ----
    char* base = (char*)d_ws;
    size_t cur = 0;
    auto allocB = [&](size_t bytes) { char* p = base + cur; cur = (cur + bytes + 255) & ~(size_t)255; return p; };
    auto allocF = [&](size_t n) { return (float*)allocB(n * 4); };
    auto allocH = [&](size_t n) { return (ushort*)allocB(n * 2); };

    // fp32
    float* h     = allocF((size_t)kMtok * kD);
    float* ssqp  = allocF((size_t)12 * kMtok);
    float* bcT   = allocF((size_t)32 * kMtok);
    float* st    = allocF((size_t)kNL * kB * kDi * kN);
    float* x768  = allocF((size_t)kMref * kD);
    float* qkvB  = allocF((size_t)kMref * 3 * kD);
    // bf16 activations
    ushort* x_bf    = allocH((size_t)kMtok * kDi);
    ushort* zT_b    = allocH((size_t)kDi * kMtok);
    ushort* xcT_b   = allocH((size_t)kDi * kMtok);
    ushort* dltT_b  = allocH((size_t)kDi * kMtok);
    ushort* xc_bf   = allocH((size_t)kMtok * kDi);
    ushort* dtin_bf = allocH((size_t)kMtok * 64);
    ushort* yb_bf   = allocH((size_t)kMtok * kDi);
    ushort* xin_bf  = allocH((size_t)kMtok * kD);
    ushort* dDi_bf  = allocH((size_t)128 * kDi);
    ushort* tb_bf   = allocH((size_t)128 * kD);
    ushort* o768_bf = allocH((size_t)128 * kD);
    ushort* f3_bf   = allocH((size_t)128 * 4 * kD);
    ushort* x768_bf = allocH((size_t)128 * kD);
    // bf16 weights
    ushort* xpw_bf  = allocH((size_t)kNL * 128 * kDi);
    ushort* dpw_bf  = allocH((size_t)kNL * kDi * 64);
    ushort* powp_bf = allocH((size_t)kD * kDi);
    ushort* qkvw_bf = allocH((size_t)3 * kD * kD);
    ushort* aow_bf  = allocH((size_t)kD * kD);
    ushort* ff1w_bf = allocH((size_t)4 * kD * kD);
    ushort* ff2w_bf = allocH((size_t)kD * 4 * kD);
    ushort* piw_bf  = allocH((size_t)kDi * kD);
    ushort* emb_bf  = allocH((size_t)kVp * kD);

    size_t base_end = cur;
    ushort* ipw_all = allocH((size_t)kNL * 2 * kDi * kD);
    ushort* opw_all = allocH((size_t)kNL * kD * kDi);
    bool full = (cur <= ws_size);
    ushort* ipw_stg = nullptr;
    ushort* opw_stg = nullptr;
    if (!full) {
        cur = base_end;
        ipw_stg = allocH((size_t)2 * kDi * kD);
        opw_stg = allocH((size_t)kD * kDi);
        if (cur > ws_size) return;
    }

    auto cvt = [&](const float* s, ushort* d, size_t n) {
        cvt_kernel<<<dim3((unsigned)((n / 4 + 255) / 256)), dim3(256), 0, stream>>>(s, d, (int)n);
    };

    hipMemsetAsync(st, 0, sizeof(float) * (size_t)kNL * kB * kDi * kN, stream);

    cvt_xpw_kernel<<<dim3(2880), dim3(256), 0, stream>>>(xpw, xpw_bf);
    cvt_dpw_kernel<<<dim3(9216), dim3(256), 0, stream>>>(dpw, dpw_bf);
    cvt(powp, powp_bf, (size_t)kD * kDi);
    cvt(qkvw, qkvw_bf, (size_t)3 * kD * kD);
    cvt(aow,  aow_bf,  (size_t)kD * kD);
    cvt(ff1w, ff1w_bf, (size_t)4 * kD * kD);
    cvt(ff2w, ff2w_bf, (size_t)kD * 4 * kD);
    cvt(piwp, piw_bf,  (size_t)kDi * kD);
    cvt(embed, emb_bf, (size_t)kV * kD);
    if (full) {
        cvt(ipw, ipw_all, (size_t)kNL * 2 * kDi * kD);
        cvt(opw, opw_all, (size_t)kNL * kD * kDi);
    }

    for (int pass = 0; pass < 2; ++pass) {
        const int* ids = pass ? a_ids : q_ids;
        const int* msk = pass ? a_msk : q_msk;

        embed_kernel<<<dim3(kMtok * kD / 256), dim3(256), 0, stream>>>(ids, msk, embed, h, ssqp);

        for (int l = 0; l < kNL; ++l) {
            const ushort* ipw_l;
            const ushort* opw_l;
            if (full) {
                ipw_l = ipw_all + (size_t)l * 2 * kDi * kD;
                opw_l = opw_all + (size_t)l * kD * kDi;
            } else {
                cvt(ipw + (size_t)l * 2 * kDi * kD, ipw_stg, (size_t)2 * kDi * kD);
                cvt(opw + (size_t)l * kD * kDi, opw_stg, (size_t)kD * kDi);
                ipw_l = ipw_stg;
                opw_l = opw_stg;
            }
            gemm_rms<<<dim3(48, 16), dim3(256), 0, stream>>>(
                h, ssqp, norm_w + (size_t)l * kD, ipw_l, kD, x_bf, zT_b, kMtok, 2 * kDi, kD);
            conv_kernel<<<dim3(kDi / 256, kMtok / 16), dim3(256), 0, stream>>>(
                x_bf, cw + (size_t)l * kDi * kK, cb + (size_t)l * kDi, xc_bf, xcT_b);
            gemm<64, 64, 0, 0, 0, 3, 3>(xc_bf, kDi, xpw_bf + (size_t)l * 128 * kDi, kDi,
                                        nullptr, 0, dtin_bf, 0, bcT,
                                        nullptr, nullptr, kMtok, 128, kDi, stream);
            gemm<64, 64, 1, 1, 0, 4, 3>(dtin_bf, 64, dpw_bf + (size_t)l * kDi * 64, 64,
                                        nullptr, 0, nullptr, 0, (float*)dltT_b,
                                        dpb + (size_t)l * kDi, nullptr, kMtok, kDi, 64, stream);
            scan_kernel<<<dim3(kB * kDi * kN / 256), dim3(256), 0, stream>>>(
                dltT_b, xcT_b, zT_b, bcT, alog + (size_t)l * kDi * kN, dpp + (size_t)l * kDi,
                st + (size_t)l * kB * kDi * kN, yb_bf);
            gemm<64, 64, 0, 0, 1, 0, 3, 1>(yb_bf, kDi, opw_l, kDi, h, kD, nullptr, 0, ssqp,
                                           nullptr, nullptr, kMtok, kD, kDi, stream);
        }

        if (pass == 0) {
            contract_kernel<<<dim3(kMref * kDi / 256), dim3(256), 0, stream>>>(st, Cwp, dDi_bf);
            for (int it = 0; it < 12; ++it) {
                gemm<64, 64, 0, 0, 0, 0, 3>(dDi_bf, kDi, powp_bf, kDi, x768, kD, nullptr, 0, nullptr,
                                            nullptr, nullptr, kMref, kD, kDi, stream);
                ln_kernel<<<dim3(kMref), dim3(256), 0, stream>>>(x768, ln1w, ln1b, tb_bf);
                gemm<64, 64, 1, 0, 0, 0, 3>(tb_bf, kD, qkvw_bf, kD, qkvB, 3 * kD, nullptr, 0, nullptr,
                                            qkvbi, nullptr, kMref, 3 * kD, kD, stream);
                attn_kernel<<<dim3(kB * kNH), dim3(32), 0, stream>>>(qkvB, o768_bf);
                gemm<64, 64, 1, 0, 1, 0, 3>(o768_bf, kD, aow_bf, kD, x768, kD, nullptr, 0, nullptr,
                                            aob, nullptr, kMref, kD, kD, stream);
                ln_kernel<<<dim3(kMref), dim3(256), 0, stream>>>(x768, ln2w, ln2b, tb_bf);
                gemm<64, 64, 1, 2, 0, 2, 3>(tb_bf, kD, ff1w_bf, kD, nullptr, 0, f3_bf, 4 * kD, nullptr,
                                            ff1b, nullptr, kMref, 4 * kD, kD, stream);
                gemm<64, 64, 1, 0, 1, 1, 3>(f3_bf, 4 * kD, ff2w_bf, 4 * kD, x768, kD, x768_bf, kD, nullptr,
                                            ff2b, nullptr, kMref, kD, 4 * kD, stream);
                gemm<64, 64, 0, 0, 0, 7, 3>(x768_bf, kD, piw_bf, kD, nullptr, 0, dDi_bf, kDi, st,
                                            Bwp, Cwp, kMref, kDi, kD, stream);
            }
        } else {
            rms_kernel<<<dim3(kMtok), dim3(256), 0, stream>>>(h, norm_f, xin_bf);
            gemm<128, 128, 0, 0, 0, 0, 2>(xin_bf, kD, emb_bf, kD, (float*)d_out, kV, nullptr, 0, nullptr,
                                          nullptr, nullptr, kMtok, kV, kD, stream);
        }
    }
}